// Round 2
// baseline (2301.346 us; speedup 1.0000x reference)
//
#include <hip/hip_runtime.h>
#include <cstdint>
#include <cstddef>

// ---------------- static problem config ----------------
#define B_   2
#define S_   2048
#define D_   1024
#define T_   4096          // B*S
#define H_   16
#define HD_  64
#define LQ_  512
#define LKV_ 256
#define FF_  1024
#define NR_  7
#define CAP_ 585

typedef unsigned int   u32;
typedef unsigned long long u64;

// ---------------- workspace layout (bytes) ----------------
// All-fp32 pipeline (reference dtype is float32); buffers reused across phases.
static constexpr size_t MB_ = 1024 * 1024;
static constexpr size_t OFF_XN   = 0;              // [T][D] f32 (xn, later xn2)
static constexpr size_t OFF_ZQ   = 16 * MB_;       // [T][LQ] f32
static constexpr size_t OFF_ZKV  = 24 * MB_;       // [T][LKV] f32
static constexpr size_t OFF_Q    = 28 * MB_;       // [T][D] f32 q  -> later act_shared [T][FF]
static constexpr size_t OFF_K    = 44 * MB_;       // [T][D] f32 k  -> later act_routed [NR][CAP][FF]
static constexpr size_t OFF_V    = 60 * MB_;       // [T][D] f32 v  -> later eout [NR][CAP][D]
static constexpr size_t OFF_ATT  = 76 * MB_;       // [T][D] f32 attn out -> later shared_out
static constexpr size_t OFF_X1   = 92 * MB_;       // [T][D] f32 residual after attention
static constexpr size_t OFF_PRI  = 108 * MB_;            // [NR][T] f32 priorities
static constexpr size_t OFF_SELI = OFF_PRI + 128 * 1024; // [NR][CAP] int
static constexpr size_t OFF_SELW = OFF_SELI + 32 * 1024; // [NR][CAP] f32
static constexpr size_t OFF_ICNT = OFF_SELW + 32 * 1024; // [T] int
static constexpr size_t OFF_IPR  = OFF_ICNT + 32 * 1024; // [T][2] int
static constexpr size_t OFF_COS  = OFF_IPR + 64 * 1024;  // [S][16] f32
static constexpr size_t OFF_SIN  = OFF_COS + 128 * 1024; // [S][16] f32
static constexpr size_t OFF_PQ   = OFF_SIN + 128 * 1024; // packed q weights [H][LQ][64] f32 (2MB)
static constexpr size_t OFF_PK   = OFF_PQ + 2 * MB_;     // packed k weights [H][LKV][64] f32 (1MB)
static constexpr size_t OFF_PV   = OFF_PK + 1 * MB_;     // packed v weights [H][LKV][64] f32 (1MB)
// total ~112.5 MB

// ---------------- RMSNorm ----------------
__global__ __launch_bounds__(256) void rmsnorm_kernel(const float* __restrict__ x,
                                                      const float* __restrict__ w,
                                                      float* __restrict__ out) {
    int t = blockIdx.x;
    int c = threadIdx.x * 4;
    float4 f = *(const float4*)(x + (size_t)t * D_ + c);
    float ss = f.x * f.x + f.y * f.y + f.z * f.z + f.w * f.w;
#pragma unroll
    for (int off = 32; off > 0; off >>= 1) ss += __shfl_down(ss, off);
    __shared__ float red[4];
    int lane = threadIdx.x & 63, wid = threadIdx.x >> 6;
    if (lane == 0) red[wid] = ss;
    __syncthreads();
    float tot = red[0] + red[1] + red[2] + red[3];
    float inv = 1.f / sqrtf(tot * (1.f / D_) + 1e-6f);
    float4 wv = *(const float4*)(w + c);
    float4 o;
    o.x = f.x * inv * wv.x;
    o.y = f.y * inv * wv.y;
    o.z = f.z * inv * wv.z;
    o.w = f.w * inv * wv.w;
    *(float4*)(out + (size_t)t * D_ + c) = o;
}

// ---------------- pack per-head projection weights ----------------
// Bq[h][k][j]: j<32 -> Wq_up[k][h*64+j] (content dims), j>=32 -> Wrot_q[k][h*64+(j-32)] (pre-rope rot dims)
__global__ __launch_bounds__(256) void pack_w_kernel(const float* __restrict__ Wq_up, const float* __restrict__ Wrot_q,
                                                     const float* __restrict__ Wk_up, const float* __restrict__ Wrot_k,
                                                     const float* __restrict__ Wv_up,
                                                     float* __restrict__ Bq, float* __restrict__ Bk, float* __restrict__ Bv) {
    int i = blockIdx.x * 256 + threadIdx.x;
    const int NQ = H_ * LQ_ * 64;   // 524288
    const int NK = H_ * LKV_ * 64;  // 262144
    if (i < NQ) {
        int j = i & 63, kk = (i >> 6) & (LQ_ - 1), h = i >> 15;
        Bq[i] = (j < 32) ? Wq_up[kk * 1024 + h * 64 + j] : Wrot_q[kk * 1024 + h * 64 + (j - 32)];
    } else if (i < NQ + NK) {
        int i2 = i - NQ;
        int j = i2 & 63, kk = (i2 >> 6) & (LKV_ - 1), h = i2 >> 14;
        Bk[i2] = (j < 32) ? Wk_up[kk * 1024 + h * 64 + j] : Wrot_k[kk * 1024 + h * 64 + (j - 32)];
    } else {
        int i3 = i - NQ - NK;
        int j = i3 & 63, kk = (i3 >> 6) & (LKV_ - 1), h = i3 >> 14;
        Bv[i3] = Wv_up[kk * 1024 + h * 64 + j];
    }
}

// ---------------- rope tables ----------------
__global__ __launch_bounds__(256) void rope_table_kernel(float* __restrict__ ct, float* __restrict__ st) {
    int i = blockIdx.x * 256 + threadIdx.x;   // S_*16
    if (i >= S_ * 16) return;
    int s = i >> 4, j = i & 15;
    float inv = 1.f / powf(10000.f, (float)j * (1.f / 16.f));
    float fr = (float)s * inv;
    ct[i] = cosf(fr);
    st[i] = sinf(fr);
}

// apply rope in place to cols [32..63] of each head slice of q and k ([T][1024] layout)
__global__ __launch_bounds__(256) void rope_apply_kernel(float* __restrict__ q, float* __restrict__ k,
                                                         const float* __restrict__ ct, const float* __restrict__ st) {
    int gid = blockIdx.x * 256 + threadIdx.x;
    if (gid >= T_ * H_) return;
    int t = gid >> 4, h = gid & 15;
    int s = t & (S_ - 1);
    float c[16], sn[16];
#pragma unroll
    for (int j = 0; j < 16; j += 4) {
        *(float4*)&c[j]  = *(const float4*)(ct + s * 16 + j);
        *(float4*)&sn[j] = *(const float4*)(st + s * 16 + j);
    }
#pragma unroll
    for (int a2 = 0; a2 < 2; a2++) {
        float* p = (a2 ? k : q) + (size_t)t * D_ + h * 64 + 32;
        float r[32], o2[32];
#pragma unroll
        for (int j2 = 0; j2 < 32; j2 += 4) *(float4*)&r[j2] = *(const float4*)(p + j2);
#pragma unroll
        for (int i = 0; i < 16; i++) {
            o2[i]      = r[i] * c[i] - r[i + 16] * sn[i];
            o2[i + 16] = r[i + 16] * c[i] + r[i] * sn[i];
        }
#pragma unroll
        for (int j2 = 0; j2 < 32; j2 += 4) *(float4*)(p + j2) = *(const float4*)&o2[j2];
    }
}

// ---------------- generic fp32 tiled GEMM: C = gather(A) @ B (*scale)(+resid) ----------------
template <int BM, int BN, bool GATHER, bool SCALE, bool RESID>
__global__ __launch_bounds__(256) void gemm_kernel(const float* __restrict__ A, const float* __restrict__ Bw,
                                                   float* __restrict__ C, const float* __restrict__ resid,
                                                   const int* __restrict__ gidx, const float* __restrict__ scale,
                                                   int M, int K, int lda, int ldb, int ldc,
                                                   long long strideA, long long strideB, long long strideC,
                                                   int gstride) {
    constexpr int TM = BM / 16, TN = BN / 16;
    constexpr int A4 = BM / 64;          // float4 A loads per thread
    constexpr int B4 = (16 * BN) / 1024; // float4 B loads per thread
    __shared__ float As[16][BM + 4];
    __shared__ float Bs[16][BN];
    const int tid = threadIdx.x, tx = tid & 15, ty = tid >> 4;
    const int z = blockIdx.z;
    const int m0 = blockIdx.y * BM, n0 = blockIdx.x * BN;
    const float* Az = A + (size_t)z * strideA;
    const float* Bz = Bw + (size_t)z * strideB;
    float* Cz = C + (size_t)z * strideC;

    int arow[A4];
#pragma unroll
    for (int i = 0; i < A4; i++) {
        int id = tid + i * 256;
        int r = m0 + (id >> 2);
        if (r > M - 1) r = M - 1;
        arow[i] = GATHER ? gidx[z * gstride + r] : r;
    }
    float acc[TM][TN];
#pragma unroll
    for (int m = 0; m < TM; m++)
#pragma unroll
        for (int n = 0; n < TN; n++) acc[m][n] = 0.f;

    for (int k0 = 0; k0 < K; k0 += 16) {
#pragma unroll
        for (int i = 0; i < A4; i++) {
            int id = tid + i * 256;
            int ar = id >> 2, ac = (id & 3) * 4;
            float4 av = *(const float4*)(Az + (size_t)arow[i] * lda + k0 + ac);
            As[ac + 0][ar] = av.x; As[ac + 1][ar] = av.y; As[ac + 2][ar] = av.z; As[ac + 3][ar] = av.w;
        }
#pragma unroll
        for (int i = 0; i < B4; i++) {
            int id = tid + i * 256;
            int br = id / (BN / 4), bc = (id % (BN / 4)) * 4;
            float4 bv = *(const float4*)(Bz + (size_t)(k0 + br) * ldb + n0 + bc);
            *(float4*)&Bs[br][bc] = bv;
        }
        __syncthreads();
#pragma unroll
        for (int kk = 0; kk < 16; kk++) {
            float a[TM], b[TN];
#pragma unroll
            for (int m = 0; m < TM; m += 4) *(float4*)&a[m] = *(const float4*)&As[kk][ty * TM + m];
#pragma unroll
            for (int n = 0; n < TN; n += 4) *(float4*)&b[n] = *(const float4*)&Bs[kk][tx * TN + n];
#pragma unroll
            for (int m = 0; m < TM; m++)
#pragma unroll
                for (int n = 0; n < TN; n++) acc[m][n] = fmaf(a[m], b[n], acc[m][n]);
        }
        __syncthreads();
    }
#pragma unroll
    for (int m = 0; m < TM; m++) {
        int r = m0 + ty * TM + m;
        if (r < M) {
            float sc = 1.f;
            if (SCALE) sc = scale[z * gstride + r];
#pragma unroll
            for (int n = 0; n < TN; n += 4) {
                int cc = n0 + tx * TN + n;
                float4 v;
                v.x = acc[m][n + 0]; v.y = acc[m][n + 1]; v.z = acc[m][n + 2]; v.w = acc[m][n + 3];
                if (SCALE) { v.x *= sc; v.y *= sc; v.z *= sc; v.w *= sc; }
                if (RESID) {
                    float4 rv = *(const float4*)(resid + (size_t)r * ldc + cc);
                    v.x += rv.x; v.y += rv.y; v.z += rv.z; v.w += rv.w;
                }
                *(float4*)(Cz + (size_t)r * ldc + cc) = v;
            }
        }
    }
}

// ---------------- SwiGLU fused GEMM: act = h1 * silu(h2), h = A @ B (B has 2*FF cols) ----------------
template <bool GATHER>
__global__ __launch_bounds__(256) void swiglu_gemm_kernel(const float* __restrict__ A, const float* __restrict__ Bw,
                                                          float* __restrict__ C, const int* __restrict__ gidx,
                                                          int M, int K, int lda, int ldb, int ldc,
                                                          long long strideB, long long strideC, int gstride) {
    // BM=128, BN=64 (act cols)
    __shared__ float As[16][132];
    __shared__ float Bs1[16][64];
    __shared__ float Bs2[16][64];
    const int tid = threadIdx.x, tx = tid & 15, ty = tid >> 4;
    const int z = blockIdx.z;
    const int m0 = blockIdx.y * 128, n0 = blockIdx.x * 64;
    const float* Bz = Bw + (size_t)z * strideB;
    float* Cz = C + (size_t)z * strideC;
    int arow[2];
#pragma unroll
    for (int i = 0; i < 2; i++) {
        int id = tid + i * 256;
        int r = m0 + (id >> 2);
        if (r > M - 1) r = M - 1;
        arow[i] = GATHER ? gidx[z * gstride + r] : r;
    }
    float c1[8][4], c2[8][4];
#pragma unroll
    for (int m = 0; m < 8; m++)
#pragma unroll
        for (int n = 0; n < 4; n++) { c1[m][n] = 0.f; c2[m][n] = 0.f; }

    for (int k0 = 0; k0 < K; k0 += 16) {
#pragma unroll
        for (int i = 0; i < 2; i++) {
            int id = tid + i * 256;
            int ar = id >> 2, ac = (id & 3) * 4;
            float4 av = *(const float4*)(A + (size_t)arow[i] * lda + k0 + ac);
            As[ac + 0][ar] = av.x; As[ac + 1][ar] = av.y; As[ac + 2][ar] = av.z; As[ac + 3][ar] = av.w;
        }
        {
            int br = tid >> 4, bc = (tid & 15) * 4;
            size_t base = (size_t)(k0 + br) * ldb + n0 + bc;
            *(float4*)&Bs1[br][bc] = *(const float4*)(Bz + base);
            *(float4*)&Bs2[br][bc] = *(const float4*)(Bz + base + FF_);
        }
        __syncthreads();
#pragma unroll
        for (int kk = 0; kk < 16; kk++) {
            float a[8], b1[4], b2[4];
            *(float4*)&a[0] = *(const float4*)&As[kk][ty * 8];
            *(float4*)&a[4] = *(const float4*)&As[kk][ty * 8 + 4];
            *(float4*)&b1[0] = *(const float4*)&Bs1[kk][tx * 4];
            *(float4*)&b2[0] = *(const float4*)&Bs2[kk][tx * 4];
#pragma unroll
            for (int m = 0; m < 8; m++)
#pragma unroll
                for (int n = 0; n < 4; n++) {
                    c1[m][n] = fmaf(a[m], b1[n], c1[m][n]);
                    c2[m][n] = fmaf(a[m], b2[n], c2[m][n]);
                }
        }
        __syncthreads();
    }
#pragma unroll
    for (int m = 0; m < 8; m++) {
        int r = m0 + ty * 8 + m;
        if (r < M) {
            float vv[4];
#pragma unroll
            for (int n = 0; n < 4; n++) {
                float g = c2[m][n];
                vv[n] = c1[m][n] * g / (1.f + expf(-g));
            }
            float4 v; v.x = vv[0]; v.y = vv[1]; v.z = vv[2]; v.w = vv[3];
            *(float4*)(Cz + (size_t)r * ldc + n0 + tx * 4) = v;
        }
    }
}

// ---------------- fp32 flash attention (causal), q/k/v in [T][H*64] layout ----------------
__global__ __launch_bounds__(256) void attn_kernel(const float* __restrict__ Q, const float* __restrict__ K,
                                                   const float* __restrict__ V, float* __restrict__ O) {
    __shared__ float Qs[64][68];    // transposed: Qs[d][r]
    __shared__ float KPs[64][68];   // K transposed, reused as P^T (P^T[c][r])
    __shared__ float Vs[64][64];    // natural: Vs[c][d]
    __shared__ float red[64][16];
    __shared__ float m_s[64], l_s[64], al_s[64];
    const int tid = threadIdx.x, tx = tid & 15, ty = tid >> 4;
    const int bh = blockIdx.y, b = bh >> 4, h = bh & 15;
    const int q0 = blockIdx.x * 64;
    const float* Qb = Q + (size_t)b * S_ * D_ + h * HD_;
    const float* Kb = K + (size_t)b * S_ * D_ + h * HD_;
    const float* Vb = V + (size_t)b * S_ * D_ + h * HD_;

    for (int idx = tid; idx < 1024; idx += 256) {
        int r = idx >> 4, c4 = (idx & 15) * 4;
        float4 qv = *(const float4*)(Qb + (size_t)(q0 + r) * D_ + c4);
        Qs[c4 + 0][r] = qv.x; Qs[c4 + 1][r] = qv.y; Qs[c4 + 2][r] = qv.z; Qs[c4 + 3][r] = qv.w;
    }
    if (tid < 64) { m_s[tid] = -3.0e38f; l_s[tid] = 0.f; }
    float o[4][4];
#pragma unroll
    for (int i = 0; i < 4; i++)
#pragma unroll
        for (int j = 0; j < 4; j++) o[i][j] = 0.f;
    __syncthreads();

    const int ntiles = blockIdx.x + 1;
    for (int kt = 0; kt < ntiles; kt++) {
        int k0 = kt * 64;
        for (int idx = tid; idx < 1024; idx += 256) {
            int r = idx >> 4, c4 = (idx & 15) * 4;
            float4 kv = *(const float4*)(Kb + (size_t)(k0 + r) * D_ + c4);
            KPs[c4 + 0][r] = kv.x; KPs[c4 + 1][r] = kv.y; KPs[c4 + 2][r] = kv.z; KPs[c4 + 3][r] = kv.w;
            *(float4*)&Vs[r][c4] = *(const float4*)(Vb + (size_t)(k0 + r) * D_ + c4);
        }
        __syncthreads();
        float s[4][4];
#pragma unroll
        for (int i = 0; i < 4; i++)
#pragma unroll
            for (int j = 0; j < 4; j++) s[i][j] = 0.f;
#pragma unroll 16
        for (int d = 0; d < 64; d++) {
            float a[4], bb[4];
            *(float4*)&a[0]  = *(const float4*)&Qs[d][ty * 4];
            *(float4*)&bb[0] = *(const float4*)&KPs[d][tx * 4];
#pragma unroll
            for (int i = 0; i < 4; i++)
#pragma unroll
                for (int j = 0; j < 4; j++) s[i][j] = fmaf(a[i], bb[j], s[i][j]);
        }
        // scale + causal mask + row max
#pragma unroll
        for (int i = 0; i < 4; i++) {
            int qq = q0 + ty * 4 + i;
            float rmax = -3.0e38f;
#pragma unroll
            for (int j = 0; j < 4; j++) {
                int kk2 = k0 + tx * 4 + j;
                float sv = s[i][j] * 0.125f + (kk2 <= qq ? 0.f : -1e9f);
                s[i][j] = sv;
                rmax = fmaxf(rmax, sv);
            }
            red[ty * 4 + i][tx] = rmax;
        }
        __syncthreads();
        if (tid < 64) {
            float m = red[tid][0];
#pragma unroll
            for (int k2 = 1; k2 < 16; k2++) m = fmaxf(m, red[tid][k2]);
            float mp = m_s[tid], mn = fmaxf(mp, m);
            al_s[tid] = expf(mp - mn);
            m_s[tid] = mn;
        }
        __syncthreads();
#pragma unroll
        for (int i = 0; i < 4; i++) {
            float mn = m_s[ty * 4 + i];
            float rsum = 0.f;
#pragma unroll
            for (int j = 0; j < 4; j++) {
                float p = expf(s[i][j] - mn);
                KPs[tx * 4 + j][ty * 4 + i] = p;   // P^T
                rsum += p;
            }
            red[ty * 4 + i][tx] = rsum;
            float al = al_s[ty * 4 + i];
#pragma unroll
            for (int j = 0; j < 4; j++) o[i][j] *= al;
        }
        __syncthreads();
        if (tid < 64) {
            float ssum = 0.f;
#pragma unroll
            for (int k2 = 0; k2 < 16; k2++) ssum += red[tid][k2];
            l_s[tid] = l_s[tid] * al_s[tid] + ssum;
        }
#pragma unroll 16
        for (int c = 0; c < 64; c++) {
            float a[4], bb[4];
            *(float4*)&a[0]  = *(const float4*)&KPs[c][ty * 4];
            *(float4*)&bb[0] = *(const float4*)&Vs[c][tx * 4];
#pragma unroll
            for (int i = 0; i < 4; i++)
#pragma unroll
                for (int j = 0; j < 4; j++) o[i][j] = fmaf(a[i], bb[j], o[i][j]);
        }
        __syncthreads();
    }
#pragma unroll
    for (int i = 0; i < 4; i++) {
        float inv = 1.f / l_s[ty * 4 + i];
        float4 v;
        v.x = o[i][0] * inv; v.y = o[i][1] * inv; v.z = o[i][2] * inv; v.w = o[i][3] * inv;
        *(float4*)(O + (size_t)(b * S_ + q0 + ty * 4 + i) * D_ + h * HD_ + tx * 4) = v;
    }
}

// ---------------- gate: affinities + top-2 membership -> priority [NR][T] ----------------
__global__ __launch_bounds__(256) void gate_kernel(const float* __restrict__ xn2, const float* __restrict__ Wg,
                                                   const float* __restrict__ bias, float* __restrict__ pri) {
    __shared__ float red[256][8];
    int t = blockIdx.x, tid = threadIdx.x;
    float acc[7] = {0.f, 0.f, 0.f, 0.f, 0.f, 0.f, 0.f};
    for (int d = tid; d < D_; d += 256) {
        float xv = xn2[(size_t)t * D_ + d];
        const float* wr = Wg + d * 7;
#pragma unroll
        for (int e = 0; e < 7; e++) acc[e] = fmaf(xv, wr[e], acc[e]);
    }
#pragma unroll
    for (int e = 0; e < 7; e++) red[tid][e] = acc[e];
    __syncthreads();
    for (int s2 = 128; s2 > 0; s2 >>= 1) {
        if (tid < s2) {
#pragma unroll
            for (int e = 0; e < 7; e++) red[tid][e] += red[tid + s2][e];
        }
        __syncthreads();
    }
    if (tid == 0) {
        float a[7];
#pragma unroll
        for (int e = 0; e < 7; e++) a[e] = 1.f / (1.f + expf(-(red[0][e] + bias[e])));
        int e1 = 0;
#pragma unroll
        for (int e = 1; e < 7; e++) if (a[e] > a[e1]) e1 = e;     // strict > : lowest-index tiebreak
        int e2 = -1;
#pragma unroll
        for (int e = 0; e < 7; e++) if (e != e1 && (e2 < 0 || a[e] > a[e2])) e2 = e;
#pragma unroll
        for (int e = 0; e < 7; e++) pri[(size_t)e * T_ + t] = (e == e1 || e == e2) ? a[e] : -1.f;
    }
}

// ---------------- per-expert capacity selection: exact top-585 via bitonic sort ----------------
// key = (aff_bits << 32) | (T-1-token): value desc, then token index asc (matches jax.lax.top_k)
__global__ __launch_bounds__(1024) void select_kernel(const float* __restrict__ pri, int* __restrict__ sel_idx,
                                                      float* __restrict__ sel_w, int* __restrict__ inv_cnt,
                                                      int* __restrict__ inv_pair) {
    __shared__ u64 keys[T_];
    const int e = blockIdx.x, tid = threadIdx.x;
    for (int i = tid; i < T_; i += 1024) {
        float p = pri[(size_t)e * T_ + i];
        keys[i] = (p > 0.f) ? ((((u64)__float_as_uint(p)) << 32) | (u32)(T_ - 1 - i)) : 0ull;
    }
    __syncthreads();
    for (int k = 2; k <= T_; k <<= 1) {
        for (int j = k >> 1; j > 0; j >>= 1) {
            for (int i = tid; i < T_; i += 1024) {
                int l = i ^ j;
                if (l > i) {
                    u64 a = keys[i], b2 = keys[l];
                    bool asc = (i & k) != 0;
                    if (asc ? (a > b2) : (a < b2)) { keys[i] = b2; keys[l] = a; }
                }
            }
            __syncthreads();
        }
    }
    if (tid < CAP_) {
        u64 kk = keys[tid];
        int tok = 0; float w = 0.f;
        if (kk) {
            tok = T_ - 1 - (int)(kk & 0xFFFFFFFFull);
            w = __uint_as_float((u32)(kk >> 32));
            int pos = atomicAdd(&inv_cnt[tok], 1);
            inv_pair[tok * 2 + pos] = e * CAP_ + tid;
        }
        sel_idx[e * CAP_ + tid] = tok;
        sel_w[e * CAP_ + tid] = w;
    }
}

// ---------------- final combine: out = x1 + shared + sum routed ----------------
__global__ __launch_bounds__(256) void final_kernel(const float* __restrict__ x1, const float* __restrict__ sh,
                                                    const float* __restrict__ eout, const int* __restrict__ icnt,
                                                    const int* __restrict__ ipair, float* __restrict__ out) {
    int t = blockIdx.x, c = threadIdx.x * 4;
    float4 v = *(const float4*)(x1 + (size_t)t * D_ + c);
    float4 s2 = *(const float4*)(sh + (size_t)t * D_ + c);
    v.x += s2.x; v.y += s2.y; v.z += s2.z; v.w += s2.w;
    int n = icnt[t];
    for (int p = 0; p < n; p++) {
        int row = ipair[t * 2 + p];
        float4 ev = *(const float4*)(eout + (size_t)row * D_ + c);
        v.x += ev.x; v.y += ev.y; v.z += ev.z; v.w += ev.w;
    }
    *(float4*)(out + (size_t)t * D_ + c) = v;
}

// ---------------- launch ----------------
extern "C" void kernel_launch(void* const* d_in, const int* in_sizes, int n_in,
                              void* d_out, int out_size, void* d_ws, size_t ws_size,
                              hipStream_t stream) {
    (void)in_sizes; (void)n_in; (void)out_size; (void)ws_size;
    const float* x       = (const float*)d_in[0];
    // d_in[1] causal_mask unused (we synthesize the -1e9 mask inline; identical values)
    const float* Wq_lat  = (const float*)d_in[2];
    const float* Wkv_lat = (const float*)d_in[3];
    const float* Wrot_q  = (const float*)d_in[4];
    const float* Wrot_k  = (const float*)d_in[5];
    const float* Wq_up   = (const float*)d_in[6];
    const float* Wk_up   = (const float*)d_in[7];
    const float* Wv_up   = (const float*)d_in[8];
    const float* Wout    = (const float*)d_in[9];
    const float* n1w     = (const float*)d_in[10];
    const float* n2w     = (const float*)d_in[11];
    const float* Ws1     = (const float*)d_in[12];
    const float* Ws2     = (const float*)d_in[13];
    const float* Wr1     = (const float*)d_in[14];
    const float* Wr2     = (const float*)d_in[15];
    const float* Wgate   = (const float*)d_in[16];
    const float* ebias   = (const float*)d_in[17];
    float* out = (float*)d_out;

    char* wsb = (char*)d_ws;
    float* xn   = (float*)(wsb + OFF_XN);
    float* zq   = (float*)(wsb + OFF_ZQ);
    float* zkv  = (float*)(wsb + OFF_ZKV);
    float* qb   = (float*)(wsb + OFF_Q);
    float* kb   = (float*)(wsb + OFF_K);
    float* vb   = (float*)(wsb + OFF_V);
    float* att  = (float*)(wsb + OFF_ATT);
    float* x1   = (float*)(wsb + OFF_X1);
    float* pri  = (float*)(wsb + OFF_PRI);
    int*   seli = (int*)(wsb + OFF_SELI);
    float* selw = (float*)(wsb + OFF_SELW);
    int*   icnt = (int*)(wsb + OFF_ICNT);
    int*   ipr  = (int*)(wsb + OFF_IPR);
    float* cost = (float*)(wsb + OFF_COS);
    float* sint = (float*)(wsb + OFF_SIN);
    float* pq   = (float*)(wsb + OFF_PQ);
    float* pk   = (float*)(wsb + OFF_PK);
    float* pv   = (float*)(wsb + OFF_PV);
    float* actS = qb;    // reuse q buffer for shared-expert activations [T][FF]
    float* actR = kb;    // reuse k buffer for routed activations [NR][CAP][FF]
    float* eout = vb;    // reuse v buffer for routed expert outputs [NR][CAP][D]
    float* shout = att;  // reuse attn buffer for shared-expert output

    // --- sublayer 1 (all fp32 for routing fidelity) ---
    rmsnorm_kernel<<<T_, 256, 0, stream>>>(x, n1w, xn);
    pack_w_kernel<<<4096, 256, 0, stream>>>(Wq_up, Wrot_q, Wk_up, Wrot_k, Wv_up, pq, pk, pv);
    rope_table_kernel<<<(S_ * 16) / 256, 256, 0, stream>>>(cost, sint);
    gemm_kernel<64, 64, false, false, false><<<dim3(8, 64, 1), 256, 0, stream>>>(
        xn, Wq_lat, zq, nullptr, nullptr, nullptr, T_, D_, D_, LQ_, LQ_, 0, 0, 0, 0);
    gemm_kernel<64, 64, false, false, false><<<dim3(4, 64, 1), 256, 0, stream>>>(
        xn, Wkv_lat, zkv, nullptr, nullptr, nullptr, T_, D_, D_, LKV_, LKV_, 0, 0, 0, 0);
    gemm_kernel<128, 64, false, false, false><<<dim3(1, 32, 16), 256, 0, stream>>>(
        zq, pq, qb, nullptr, nullptr, nullptr, T_, LQ_, LQ_, 64, D_, 0, (long long)LQ_ * 64, 64, 0);
    gemm_kernel<128, 64, false, false, false><<<dim3(1, 32, 16), 256, 0, stream>>>(
        zkv, pk, kb, nullptr, nullptr, nullptr, T_, LKV_, LKV_, 64, D_, 0, (long long)LKV_ * 64, 64, 0);
    gemm_kernel<128, 64, false, false, false><<<dim3(1, 32, 16), 256, 0, stream>>>(
        zkv, pv, vb, nullptr, nullptr, nullptr, T_, LKV_, LKV_, 64, D_, 0, (long long)LKV_ * 64, 64, 0);
    rope_apply_kernel<<<(T_ * H_) / 256, 256, 0, stream>>>(qb, kb, cost, sint);
    attn_kernel<<<dim3(S_ / 64, B_ * H_), 256, 0, stream>>>(qb, kb, vb, att);
    gemm_kernel<128, 128, false, false, true><<<dim3(8, 32, 1), 256, 0, stream>>>(
        att, Wout, x1, x, nullptr, nullptr, T_, D_, D_, D_, D_, 0, 0, 0, 0);

    // --- sublayer 2: MoE ---
    rmsnorm_kernel<<<T_, 256, 0, stream>>>(x1, n2w, xn);   // xn now = xn2
    hipMemsetAsync(icnt, 0, T_ * sizeof(int), stream);
    gate_kernel<<<T_, 256, 0, stream>>>(xn, Wgate, ebias, pri);
    select_kernel<<<NR_, 1024, 0, stream>>>(pri, seli, selw, icnt, ipr);
    // shared expert
    swiglu_gemm_kernel<false><<<dim3(16, 32, 1), 256, 0, stream>>>(
        xn, Ws1, actS, nullptr, T_, D_, D_, 2 * FF_, FF_, 0, 0, 0);
    gemm_kernel<128, 128, false, false, false><<<dim3(8, 32, 1), 256, 0, stream>>>(
        actS, Ws2, shout, nullptr, nullptr, nullptr, T_, FF_, FF_, D_, D_, 0, 0, 0, 0);
    // routed experts (grouped, gathered)
    swiglu_gemm_kernel<true><<<dim3(16, 5, NR_), 256, 0, stream>>>(
        xn, Wr1, actR, seli, CAP_, D_, D_, 2 * FF_, FF_,
        (long long)D_ * 2 * FF_, (long long)CAP_ * FF_, CAP_);
    gemm_kernel<128, 128, false, true, false><<<dim3(8, 5, NR_), 256, 0, stream>>>(
        actR, Wr2, eout, nullptr, nullptr, selw, CAP_, FF_, FF_, D_, D_,
        (long long)CAP_ * FF_, (long long)FF_ * D_, (long long)CAP_ * D_, CAP_);
    // combine
    final_kernel<<<T_, 256, 0, stream>>>(x1, shout, eout, icnt, ipr, out);
}

// Round 3
// 1231.591 us; speedup vs baseline: 1.8686x; 1.8686x over previous
//
#include <hip/hip_runtime.h>
#include <cstdint>
#include <cstddef>

// ---------------- static problem config ----------------
#define B_   2
#define S_   2048
#define D_   1024
#define T_   4096          // B*S
#define H_   16
#define HD_  64
#define LQ_  512
#define LKV_ 256
#define FF_  1024
#define NR_  7
#define CAP_ 585

typedef unsigned int   u32;
typedef unsigned long long u64;
typedef __bf16 bf16_t;
typedef __bf16 bf16x8 __attribute__((ext_vector_type(8)));
typedef float  f32x4  __attribute__((ext_vector_type(4)));

// ---------------- workspace layout (bytes) ----------------
// fp32 through the attention path (routing fidelity); bf16 MFMA for experts.
// Regions are phase-reused; total ~112.5 MB.
static constexpr size_t MB_ = 1024 * 1024;
static constexpr size_t OFF_XN   = 0;              // [T][D] f32 xn/xn2 -> later Wr2T bf16 (14.7MB)
static constexpr size_t OFF_ZQ   = 16 * MB_;       // [T][LQ] f32 -> later xnb bf16 [T][D] (8MB)
static constexpr size_t OFF_ZKV  = 24 * MB_;       // [T][LKV] f32 -> later Ws1T bf16 (4MB)
static constexpr size_t OFF_Q    = 28 * MB_;       // [T][D] f32 q -> later h bf16 [4096][2048] (16MB)
static constexpr size_t OFF_K    = 44 * MB_;       // [T][D] f32 k -> later act bf16 [.][FF] (8.4MB)
static constexpr size_t OFF_V    = 60 * MB_;       // [T][D] f32 v -> later eout f32 [4095][D] (16.77MB)
static constexpr size_t OFF_ATT  = 76 * MB_;       // [T][D] f32 attn out -> Wr1T-half bf16 -> shout f32
static constexpr size_t OFF_X1   = 92 * MB_;       // [T][D] f32 residual after attention
static constexpr size_t OFF_PRI  = 108 * MB_;            // [NR][T] f32 priorities
static constexpr size_t OFF_SELI = OFF_PRI + 128 * 1024; // [NR][CAP] int
static constexpr size_t OFF_SELW = OFF_SELI + 32 * 1024; // [NR][CAP] f32
static constexpr size_t OFF_ICNT = OFF_SELW + 32 * 1024; // [T] int
static constexpr size_t OFF_IPR  = OFF_ICNT + 32 * 1024; // [T][2] int
static constexpr size_t OFF_COS  = OFF_IPR + 64 * 1024;  // [S][16] f32
static constexpr size_t OFF_SIN  = OFF_COS + 128 * 1024; // [S][16] f32
static constexpr size_t OFF_PQ   = OFF_SIN + 128 * 1024; // packed q weights f32 (2MB) -> later Ws2T bf16
static constexpr size_t OFF_PK   = OFF_PQ + 2 * MB_;     // packed k weights f32 (1MB)
static constexpr size_t OFF_PV   = OFF_PK + 1 * MB_;     // packed v weights f32 (1MB)

// ---------------- RMSNorm ----------------
__global__ __launch_bounds__(256) void rmsnorm_kernel(const float* __restrict__ x,
                                                      const float* __restrict__ w,
                                                      float* __restrict__ out) {
    int t = blockIdx.x;
    int c = threadIdx.x * 4;
    float4 f = *(const float4*)(x + (size_t)t * D_ + c);
    float ss = f.x * f.x + f.y * f.y + f.z * f.z + f.w * f.w;
#pragma unroll
    for (int off = 32; off > 0; off >>= 1) ss += __shfl_down(ss, off);
    __shared__ float red[4];
    int lane = threadIdx.x & 63, wid = threadIdx.x >> 6;
    if (lane == 0) red[wid] = ss;
    __syncthreads();
    float tot = red[0] + red[1] + red[2] + red[3];
    float inv = 1.f / sqrtf(tot * (1.f / D_) + 1e-6f);
    float4 wv = *(const float4*)(w + c);
    float4 o;
    o.x = f.x * inv * wv.x;
    o.y = f.y * inv * wv.y;
    o.z = f.z * inv * wv.z;
    o.w = f.w * inv * wv.w;
    *(float4*)(out + (size_t)t * D_ + c) = o;
}

// ---------------- pack per-head projection weights (fp32, attention path) ----------------
__global__ __launch_bounds__(256) void pack_w_kernel(const float* __restrict__ Wq_up, const float* __restrict__ Wrot_q,
                                                     const float* __restrict__ Wk_up, const float* __restrict__ Wrot_k,
                                                     const float* __restrict__ Wv_up,
                                                     float* __restrict__ Bq, float* __restrict__ Bk, float* __restrict__ Bv) {
    int i = blockIdx.x * 256 + threadIdx.x;
    const int NQ = H_ * LQ_ * 64;   // 524288
    const int NK = H_ * LKV_ * 64;  // 262144
    if (i < NQ) {
        int j = i & 63, kk = (i >> 6) & (LQ_ - 1), h = i >> 15;
        Bq[i] = (j < 32) ? Wq_up[kk * 1024 + h * 64 + j] : Wrot_q[kk * 1024 + h * 64 + (j - 32)];
    } else if (i < NQ + NK) {
        int i2 = i - NQ;
        int j = i2 & 63, kk = (i2 >> 6) & (LKV_ - 1), h = i2 >> 14;
        Bk[i2] = (j < 32) ? Wk_up[kk * 1024 + h * 64 + j] : Wrot_k[kk * 1024 + h * 64 + (j - 32)];
    } else {
        int i3 = i - NQ - NK;
        int j = i3 & 63, kk = (i3 >> 6) & (LKV_ - 1), h = i3 >> 14;
        Bv[i3] = Wv_up[kk * 1024 + h * 64 + j];
    }
}

// ---------------- rope tables ----------------
__global__ __launch_bounds__(256) void rope_table_kernel(float* __restrict__ ct, float* __restrict__ st) {
    int i = blockIdx.x * 256 + threadIdx.x;   // S_*16
    if (i >= S_ * 16) return;
    int s = i >> 4, j = i & 15;
    float inv = 1.f / powf(10000.f, (float)j * (1.f / 16.f));
    float fr = (float)s * inv;
    ct[i] = cosf(fr);
    st[i] = sinf(fr);
}

// apply rope in place to cols [32..63] of each head slice of q and k ([T][1024] layout)
__global__ __launch_bounds__(256) void rope_apply_kernel(float* __restrict__ q, float* __restrict__ k,
                                                         const float* __restrict__ ct, const float* __restrict__ st) {
    int gid = blockIdx.x * 256 + threadIdx.x;
    if (gid >= T_ * H_) return;
    int t = gid >> 4, h = gid & 15;
    int s = t & (S_ - 1);
    float c[16], sn[16];
#pragma unroll
    for (int j = 0; j < 16; j += 4) {
        *(float4*)&c[j]  = *(const float4*)(ct + s * 16 + j);
        *(float4*)&sn[j] = *(const float4*)(st + s * 16 + j);
    }
#pragma unroll
    for (int a2 = 0; a2 < 2; a2++) {
        float* p = (a2 ? k : q) + (size_t)t * D_ + h * 64 + 32;
        float r[32], o2[32];
#pragma unroll
        for (int j2 = 0; j2 < 32; j2 += 4) *(float4*)&r[j2] = *(const float4*)(p + j2);
#pragma unroll
        for (int i = 0; i < 16; i++) {
            o2[i]      = r[i] * c[i] - r[i + 16] * sn[i];
            o2[i + 16] = r[i + 16] * c[i] + r[i] * sn[i];
        }
#pragma unroll
        for (int j2 = 0; j2 < 32; j2 += 4) *(float4*)(p + j2) = *(const float4*)&o2[j2];
    }
}

// ---------------- generic fp32 tiled GEMM: C = A @ B (+resid)  (attention path only) ----------------
template <int BM, int BN, bool RESID>
__global__ __launch_bounds__(256) void gemm_kernel(const float* __restrict__ A, const float* __restrict__ Bw,
                                                   float* __restrict__ C, const float* __restrict__ resid,
                                                   int M, int K, int lda, int ldb, int ldc,
                                                   long long strideB, long long strideC) {
    constexpr int TM = BM / 16, TN = BN / 16;
    constexpr int A4 = BM / 64;          // float4 A loads per thread
    constexpr int B4 = (16 * BN) / 1024; // float4 B loads per thread
    __shared__ float As[16][BM + 4];
    __shared__ float Bs[16][BN];
    const int tid = threadIdx.x, tx = tid & 15, ty = tid >> 4;
    const int z = blockIdx.z;
    const int m0 = blockIdx.y * BM, n0 = blockIdx.x * BN;
    const float* Bz = Bw + (size_t)z * strideB;
    float* Cz = C + (size_t)z * strideC;

    float acc[TM][TN];
#pragma unroll
    for (int m = 0; m < TM; m++)
#pragma unroll
        for (int n = 0; n < TN; n++) acc[m][n] = 0.f;

    for (int k0 = 0; k0 < K; k0 += 16) {
#pragma unroll
        for (int i = 0; i < A4; i++) {
            int id = tid + i * 256;
            int ar = id >> 2, ac = (id & 3) * 4;
            int r = m0 + ar; if (r > M - 1) r = M - 1;
            float4 av = *(const float4*)(A + (size_t)r * lda + k0 + ac);
            As[ac + 0][ar] = av.x; As[ac + 1][ar] = av.y; As[ac + 2][ar] = av.z; As[ac + 3][ar] = av.w;
        }
#pragma unroll
        for (int i = 0; i < B4; i++) {
            int id = tid + i * 256;
            int br = id / (BN / 4), bc = (id % (BN / 4)) * 4;
            float4 bv = *(const float4*)(Bz + (size_t)(k0 + br) * ldb + n0 + bc);
            *(float4*)&Bs[br][bc] = bv;
        }
        __syncthreads();
#pragma unroll
        for (int kk = 0; kk < 16; kk++) {
            float a[TM], b[TN];
#pragma unroll
            for (int m = 0; m < TM; m += 4) *(float4*)&a[m] = *(const float4*)&As[kk][ty * TM + m];
#pragma unroll
            for (int n = 0; n < TN; n += 4) *(float4*)&b[n] = *(const float4*)&Bs[kk][tx * TN + n];
#pragma unroll
            for (int m = 0; m < TM; m++)
#pragma unroll
                for (int n = 0; n < TN; n++) acc[m][n] = fmaf(a[m], b[n], acc[m][n]);
        }
        __syncthreads();
    }
#pragma unroll
    for (int m = 0; m < TM; m++) {
        int r = m0 + ty * TM + m;
        if (r < M) {
#pragma unroll
            for (int n = 0; n < TN; n += 4) {
                int cc = n0 + tx * TN + n;
                float4 v;
                v.x = acc[m][n + 0]; v.y = acc[m][n + 1]; v.z = acc[m][n + 2]; v.w = acc[m][n + 3];
                if (RESID) {
                    float4 rv = *(const float4*)(resid + (size_t)r * ldc + cc);
                    v.x += rv.x; v.y += rv.y; v.z += rv.z; v.w += rv.w;
                }
                *(float4*)(Cz + (size_t)r * ldc + cc) = v;
            }
        }
    }
}

// ---------------- fp32 flash attention (causal), LPT-scheduled, register softmax ----------------
__global__ __launch_bounds__(256) void attn_kernel(const float* __restrict__ Q, const float* __restrict__ K,
                                                   const float* __restrict__ V, float* __restrict__ O) {
    __shared__ float Qs[64][68];    // Q transposed: Qs[d][r]
    __shared__ float Ks[64][68];    // K transposed Ks[d][c]; reused as P^T[c][r] after QK
    __shared__ float Vs[64][64];    // natural: Vs[c][d]
    const int tid = threadIdx.x, tx = tid & 15, ty = tid >> 4;
    const int jb = blockIdx.x;
    const int qt = 31 - (jb >> 5);          // LPT: heaviest q-tiles first
    const int bh = jb & 31, b = bh >> 4, h = bh & 15;
    const int q0 = qt * 64;
    const float* Qb = Q + (size_t)b * S_ * D_ + h * HD_;
    const float* Kb = K + (size_t)b * S_ * D_ + h * HD_;
    const float* Vb = V + (size_t)b * S_ * D_ + h * HD_;

    for (int idx = tid; idx < 1024; idx += 256) {
        int r = idx >> 4, c4 = (idx & 15) * 4;
        float4 qv = *(const float4*)(Qb + (size_t)(q0 + r) * D_ + c4);
        Qs[c4 + 0][r] = qv.x; Qs[c4 + 1][r] = qv.y; Qs[c4 + 2][r] = qv.z; Qs[c4 + 3][r] = qv.w;
    }
    float m_r[4], l_r[4], o[4][4];
#pragma unroll
    for (int i = 0; i < 4; i++) {
        m_r[i] = -3.0e38f; l_r[i] = 0.f;
#pragma unroll
        for (int j = 0; j < 4; j++) o[i][j] = 0.f;
    }
    __syncthreads();

    for (int kt = 0; kt <= qt; kt++) {
        int k0 = kt * 64;
        for (int idx = tid; idx < 1024; idx += 256) {
            int r = idx >> 4, c4 = (idx & 15) * 4;
            float4 kv = *(const float4*)(Kb + (size_t)(k0 + r) * D_ + c4);
            Ks[c4 + 0][r] = kv.x; Ks[c4 + 1][r] = kv.y; Ks[c4 + 2][r] = kv.z; Ks[c4 + 3][r] = kv.w;
            *(float4*)&Vs[r][c4] = *(const float4*)(Vb + (size_t)(k0 + r) * D_ + c4);
        }
        __syncthreads();
        float s[4][4];
#pragma unroll
        for (int i = 0; i < 4; i++)
#pragma unroll
            for (int j = 0; j < 4; j++) s[i][j] = 0.f;
#pragma unroll 16
        for (int d = 0; d < 64; d++) {
            float a[4], bb[4];
            *(float4*)&a[0]  = *(const float4*)&Qs[d][ty * 4];
            *(float4*)&bb[0] = *(const float4*)&Ks[d][tx * 4];
#pragma unroll
            for (int i = 0; i < 4; i++)
#pragma unroll
                for (int j = 0; j < 4; j++) s[i][j] = fmaf(a[i], bb[j], s[i][j]);
        }
        // scale + causal mask + register/shuffle softmax (row group = 16 lanes sharing ty)
        float e[4][4];
#pragma unroll
        for (int i = 0; i < 4; i++) {
            int qq = q0 + ty * 4 + i;
            float rmax = -3.0e38f;
#pragma unroll
            for (int j = 0; j < 4; j++) {
                int kk2 = k0 + tx * 4 + j;
                float sv = s[i][j] * 0.125f + (kk2 <= qq ? 0.f : -1e9f);
                s[i][j] = sv;
                rmax = fmaxf(rmax, sv);
            }
#pragma unroll
            for (int off = 1; off < 16; off <<= 1) rmax = fmaxf(rmax, __shfl_xor(rmax, off));
            float mn = fmaxf(m_r[i], rmax);
            float al = expf(m_r[i] - mn);
            m_r[i] = mn;
            float rs = 0.f;
#pragma unroll
            for (int j = 0; j < 4; j++) { float p = expf(s[i][j] - mn); e[i][j] = p; rs += p; }
#pragma unroll
            for (int off = 1; off < 16; off <<= 1) rs += __shfl_xor(rs, off);
            l_r[i] = l_r[i] * al + rs;
#pragma unroll
            for (int j = 0; j < 4; j++) o[i][j] *= al;
        }
        __syncthreads();   // all waves done reading Ks (QK); safe to overwrite with P^T
        // write P^T into Ks: P^T[c][r], float4 along r (wave-local rows; consumed by same wave)
#pragma unroll
        for (int j = 0; j < 4; j++) {
            float4 pv; pv.x = e[0][j]; pv.y = e[1][j]; pv.z = e[2][j]; pv.w = e[3][j];
            *(float4*)&Ks[tx * 4 + j][ty * 4] = pv;
        }
#pragma unroll 16
        for (int c = 0; c < 64; c++) {
            float a[4], bb[4];
            *(float4*)&a[0]  = *(const float4*)&Ks[c][ty * 4];   // P^T[c][own rows] (broadcast)
            *(float4*)&bb[0] = *(const float4*)&Vs[c][tx * 4];
#pragma unroll
            for (int i = 0; i < 4; i++)
#pragma unroll
                for (int j = 0; j < 4; j++) o[i][j] = fmaf(a[i], bb[j], o[i][j]);
        }
        __syncthreads();   // before next tile overwrites Ks/Vs
    }
#pragma unroll
    for (int i = 0; i < 4; i++) {
        float inv = 1.f / l_r[i];
        float4 v;
        v.x = o[i][0] * inv; v.y = o[i][1] * inv; v.z = o[i][2] * inv; v.w = o[i][3] * inv;
        *(float4*)(O + (size_t)(b * S_ + q0 + ty * 4 + i) * D_ + h * HD_ + tx * 4) = v;
    }
}

// ---------------- gate: affinities + top-2 membership -> priority [NR][T] ----------------
__global__ __launch_bounds__(256) void gate_kernel(const float* __restrict__ xn2, const float* __restrict__ Wg,
                                                   const float* __restrict__ bias, float* __restrict__ pri) {
    __shared__ float red[256][8];
    int t = blockIdx.x, tid = threadIdx.x;
    float acc[7] = {0.f, 0.f, 0.f, 0.f, 0.f, 0.f, 0.f};
    for (int d = tid; d < D_; d += 256) {
        float xv = xn2[(size_t)t * D_ + d];
        const float* wr = Wg + d * 7;
#pragma unroll
        for (int e = 0; e < 7; e++) acc[e] = fmaf(xv, wr[e], acc[e]);
    }
#pragma unroll
    for (int e = 0; e < 7; e++) red[tid][e] = acc[e];
    __syncthreads();
    for (int s2 = 128; s2 > 0; s2 >>= 1) {
        if (tid < s2) {
#pragma unroll
            for (int e = 0; e < 7; e++) red[tid][e] += red[tid + s2][e];
        }
        __syncthreads();
    }
    if (tid == 0) {
        float a[7];
#pragma unroll
        for (int e = 0; e < 7; e++) a[e] = 1.f / (1.f + expf(-(red[0][e] + bias[e])));
        int e1 = 0;
#pragma unroll
        for (int e = 1; e < 7; e++) if (a[e] > a[e1]) e1 = e;     // strict > : lowest-index tiebreak
        int e2 = -1;
#pragma unroll
        for (int e = 0; e < 7; e++) if (e != e1 && (e2 < 0 || a[e] > a[e2])) e2 = e;
#pragma unroll
        for (int e = 0; e < 7; e++) pri[(size_t)e * T_ + t] = (e == e1 || e == e2) ? a[e] : -1.f;
    }
}

// ---------------- per-expert capacity selection: exact top-585 via bitonic sort ----------------
__global__ __launch_bounds__(1024) void select_kernel(const float* __restrict__ pri, int* __restrict__ sel_idx,
                                                      float* __restrict__ sel_w, int* __restrict__ inv_cnt,
                                                      int* __restrict__ inv_pair) {
    __shared__ u64 keys[T_];
    const int e = blockIdx.x, tid = threadIdx.x;
    for (int i = tid; i < T_; i += 1024) {
        float p = pri[(size_t)e * T_ + i];
        keys[i] = (p > 0.f) ? ((((u64)__float_as_uint(p)) << 32) | (u32)(T_ - 1 - i)) : 0ull;
    }
    __syncthreads();
    for (int k = 2; k <= T_; k <<= 1) {
        for (int j = k >> 1; j > 0; j >>= 1) {
            for (int i = tid; i < T_; i += 1024) {
                int l = i ^ j;
                if (l > i) {
                    u64 a = keys[i], b2 = keys[l];
                    bool asc = (i & k) != 0;
                    if (asc ? (a > b2) : (a < b2)) { keys[i] = b2; keys[l] = a; }
                }
            }
            __syncthreads();
        }
    }
    if (tid < CAP_) {
        u64 kk = keys[tid];
        int tok = 0; float w = 0.f;
        if (kk) {
            tok = T_ - 1 - (int)(kk & 0xFFFFFFFFull);
            w = __uint_as_float((u32)(kk >> 32));
            int pos = atomicAdd(&inv_cnt[tok], 1);
            inv_pair[tok * 2 + pos] = e * CAP_ + tid;
        }
        sel_idx[e * CAP_ + tid] = tok;
        sel_w[e * CAP_ + tid] = w;
    }
}

// ---------------- f32 -> bf16 bulk convert ----------------
__global__ __launch_bounds__(256) void cvt_bf16_kernel(const float* __restrict__ in, bf16_t* __restrict__ out,
                                                       int n8) {
    int i8 = blockIdx.x * 256 + threadIdx.x;
    if (i8 >= n8) return;
    size_t base = (size_t)i8 * 8;
    float4 a = *(const float4*)(in + base);
    float4 b = *(const float4*)(in + base + 4);
    bf16x8 o;
    o[0] = (bf16_t)a.x; o[1] = (bf16_t)a.y; o[2] = (bf16_t)a.z; o[3] = (bf16_t)a.w;
    o[4] = (bf16_t)b.x; o[5] = (bf16_t)b.y; o[6] = (bf16_t)b.z; o[7] = (bf16_t)b.w;
    *(bf16x8*)(out + base) = o;
}

// ---------------- transpose + convert: out[z][n][k] = (bf16) in[z][k][nbase+n] ----------------
__global__ __launch_bounds__(256) void packT_kernel(const float* __restrict__ in, bf16_t* __restrict__ out,
                                                    int K, int N, int nbase,
                                                    long long inStride, long long outStride) {
    __shared__ float tile[32][33];
    const int z = blockIdx.z;
    const int k0 = blockIdx.x * 32, n0 = blockIdx.y * 32;
    const int rr = threadIdx.x >> 5, cc = threadIdx.x & 31;
    const float* inz = in + (size_t)z * inStride;
#pragma unroll
    for (int it = 0; it < 4; it++) {
        int k = k0 + rr + it * 8;
        tile[rr + it * 8][cc] = inz[(size_t)k * N + nbase + n0 + cc];
    }
    __syncthreads();
    bf16_t* outz = out + (size_t)z * outStride;
#pragma unroll
    for (int it = 0; it < 4; it++) {
        int nl = n0 + rr + it * 8;
        outz[(size_t)nl * K + k0 + cc] = (bf16_t)tile[cc][rr + it * 8];
    }
}

// ---------------- bf16 MFMA GEMM: C = gather(A) @ Bt^T (*scale), 128x128 tile, K-step 32 ----------------
template <bool GATHER, bool SCALE, bool OUTBF16>
__global__ __launch_bounds__(256) void mfma_gemm_kernel(const bf16_t* __restrict__ A, const bf16_t* __restrict__ Bt,
                                                        void* __restrict__ Cv,
                                                        const int* __restrict__ gidx, const float* __restrict__ scale,
                                                        int M, int K, int lda, int ldc,
                                                        long long strideA, long long strideBt, long long strideC,
                                                        int gstride) {
    __shared__ __align__(16) bf16_t As[128 * 32];
    __shared__ __align__(16) bf16_t Bs[128 * 32];
    const int tid = threadIdx.x;
    const int lane = tid & 63, w = tid >> 6;
    const int wm = (w & 1) * 64, wn = (w >> 1) * 64;
    const int z = blockIdx.z;
    const int m0 = blockIdx.y * 128, n0 = blockIdx.x * 128;
    const bf16_t* Az = A + (GATHER ? 0 : (size_t)z * strideA);
    const bf16_t* Bz = Bt + (size_t)z * strideBt;

    int arow[2];
#pragma unroll
    for (int i = 0; i < 2; i++) {
        int chunk = tid + i * 256;
        int r = m0 + (chunk >> 2);
        if (r > M - 1) r = M - 1;
        arow[i] = GATHER ? gidx[z * gstride + r] : r;
    }

    f32x4 acc[4][4];
#pragma unroll
    for (int mi = 0; mi < 4; mi++)
#pragma unroll
        for (int ni = 0; ni < 4; ni++) { f32x4 zz = {0.f, 0.f, 0.f, 0.f}; acc[mi][ni] = zz; }

    const int mrow = lane & 15, q = lane >> 4;
    for (int k0 = 0; k0 < K; k0 += 32) {
#pragma unroll
        for (int i = 0; i < 2; i++) {
            int chunk = tid + i * 256;
            int row = chunk >> 2, koff = (chunk & 3) * 8;
            *(uint4*)(As + row * 32 + koff) = *(const uint4*)(Az + (size_t)arow[i] * lda + k0 + koff);
            *(uint4*)(Bs + row * 32 + koff) = *(const uint4*)(Bz + (size_t)(n0 + row) * K + k0 + koff);
        }
        __syncthreads();
        bf16x8 af[4], bfr[4];
#pragma unroll
        for (int mi = 0; mi < 4; mi++)
            af[mi] = *(const bf16x8*)(As + (wm + mi * 16 + mrow) * 32 + q * 8);
#pragma unroll
        for (int ni = 0; ni < 4; ni++)
            bfr[ni] = *(const bf16x8*)(Bs + (wn + ni * 16 + mrow) * 32 + q * 8);
#pragma unroll
        for (int mi = 0; mi < 4; mi++)
#pragma unroll
            for (int ni = 0; ni < 4; ni++)
                acc[mi][ni] = __builtin_amdgcn_mfma_f32_16x16x32_bf16(af[mi], bfr[ni], acc[mi][ni], 0, 0, 0);
        __syncthreads();
    }
    // epilogue: C/D layout col = lane&15, row = (lane>>4)*4 + v
#pragma unroll
    for (int mi = 0; mi < 4; mi++) {
        int rbase = m0 + wm + mi * 16 + q * 4;
#pragma unroll
        for (int v = 0; v < 4; v++) {
            int r = rbase + v;
            if (r < M) {
                float sc = SCALE ? scale[z * gstride + r] : 1.f;
#pragma unroll
                for (int ni = 0; ni < 4; ni++) {
                    int c = n0 + wn + ni * 16 + mrow;
                    float val = acc[mi][ni][v];
                    if (SCALE) val *= sc;
                    size_t off = (size_t)z * strideC + (size_t)r * ldc + c;
                    if (OUTBF16) ((bf16_t*)Cv)[off] = (bf16_t)val;
                    else         ((float*)Cv)[off] = val;
                }
            }
        }
    }
}

// ---------------- SwiGLU elementwise: act[r][f] = h1 * silu(h2), h = [rows][2048] bf16 ----------------
__global__ __launch_bounds__(256) void swiglu_kernel(const bf16_t* __restrict__ h, bf16_t* __restrict__ act,
                                                     int rows) {
    int i8 = blockIdx.x * 256 + threadIdx.x;
    int total = rows * 128;
    if (i8 >= total) return;
    int r = i8 >> 7, f = (i8 & 127) * 8;
    bf16x8 h1 = *(const bf16x8*)(h + (size_t)r * 2048 + f);
    bf16x8 h2 = *(const bf16x8*)(h + (size_t)r * 2048 + 1024 + f);
    bf16x8 o;
#pragma unroll
    for (int j = 0; j < 8; j++) {
        float a = (float)h1[j], g = (float)h2[j];
        o[j] = (bf16_t)(a * g / (1.f + expf(-g)));
    }
    *(bf16x8*)(act + (size_t)r * 1024 + f) = o;
}

// ---------------- final combine: out = x1 + shared + sum routed ----------------
__global__ __launch_bounds__(256) void final_kernel(const float* __restrict__ x1, const float* __restrict__ sh,
                                                    const float* __restrict__ eout, const int* __restrict__ icnt,
                                                    const int* __restrict__ ipair, float* __restrict__ out) {
    int t = blockIdx.x, c = threadIdx.x * 4;
    float4 v = *(const float4*)(x1 + (size_t)t * D_ + c);
    float4 s2 = *(const float4*)(sh + (size_t)t * D_ + c);
    v.x += s2.x; v.y += s2.y; v.z += s2.z; v.w += s2.w;
    int n = icnt[t];
    for (int p = 0; p < n; p++) {
        int row = ipair[t * 2 + p];
        float4 ev = *(const float4*)(eout + (size_t)row * D_ + c);
        v.x += ev.x; v.y += ev.y; v.z += ev.z; v.w += ev.w;
    }
    *(float4*)(out + (size_t)t * D_ + c) = v;
}

// ---------------- launch ----------------
extern "C" void kernel_launch(void* const* d_in, const int* in_sizes, int n_in,
                              void* d_out, int out_size, void* d_ws, size_t ws_size,
                              hipStream_t stream) {
    (void)in_sizes; (void)n_in; (void)out_size; (void)ws_size;
    const float* x       = (const float*)d_in[0];
    const float* Wq_lat  = (const float*)d_in[2];
    const float* Wkv_lat = (const float*)d_in[3];
    const float* Wq_up   = (const float*)d_in[6];
    const float* Wk_up   = (const float*)d_in[7];
    const float* Wv_up   = (const float*)d_in[8];
    const float* Wrot_q  = (const float*)d_in[4];
    const float* Wrot_k  = (const float*)d_in[5];
    const float* Wout    = (const float*)d_in[9];
    const float* n1w     = (const float*)d_in[10];
    const float* n2w     = (const float*)d_in[11];
    const float* Ws1     = (const float*)d_in[12];
    const float* Ws2     = (const float*)d_in[13];
    const float* Wr1     = (const float*)d_in[14];
    const float* Wr2     = (const float*)d_in[15];
    const float* Wgate   = (const float*)d_in[16];
    const float* ebias   = (const float*)d_in[17];
    float* out = (float*)d_out;

    char* wsb = (char*)d_ws;
    float* xn   = (float*)(wsb + OFF_XN);
    float* zq   = (float*)(wsb + OFF_ZQ);
    float* zkv  = (float*)(wsb + OFF_ZKV);
    float* qb   = (float*)(wsb + OFF_Q);
    float* kb   = (float*)(wsb + OFF_K);
    float* vb   = (float*)(wsb + OFF_V);
    float* att  = (float*)(wsb + OFF_ATT);
    float* x1   = (float*)(wsb + OFF_X1);
    float* pri  = (float*)(wsb + OFF_PRI);
    int*   seli = (int*)(wsb + OFF_SELI);
    float* selw = (float*)(wsb + OFF_SELW);
    int*   icnt = (int*)(wsb + OFF_ICNT);
    int*   ipr  = (int*)(wsb + OFF_IPR);
    float* cost = (float*)(wsb + OFF_COS);
    float* sint = (float*)(wsb + OFF_SIN);
    float* pq   = (float*)(wsb + OFF_PQ);
    float* pk   = (float*)(wsb + OFF_PK);
    float* pv   = (float*)(wsb + OFF_PV);
    // MoE-phase aliases (bf16 / f32 reuse of dead regions)
    bf16_t* xnb  = (bf16_t*)(wsb + OFF_ZQ);    // [T][D] bf16
    bf16_t* Ws1T = (bf16_t*)(wsb + OFF_ZKV);   // [2048][1024] bf16
    bf16_t* Ws2T = (bf16_t*)(wsb + OFF_PQ);    // [1024][1024] bf16
    bf16_t* Wr2T = (bf16_t*)(wsb + OFF_XN);    // [7][1024][1024] bf16
    bf16_t* Wr1H = (bf16_t*)(wsb + OFF_ATT);   // [7][1024][1024] bf16 (one N-half at a time)
    bf16_t* hbuf = (bf16_t*)(wsb + OFF_Q);     // [rows][2048] bf16
    bf16_t* actb = (bf16_t*)(wsb + OFF_K);     // [rows][1024] bf16
    float*  eout = (float*)(wsb + OFF_V);      // [7*585][1024] f32
    float*  shout = (float*)(wsb + OFF_ATT);   // [T][1024] f32 (after Wr1H dead)

    // --- sublayer 1: attention path, all fp32 (routing fidelity) ---
    rmsnorm_kernel<<<T_, 256, 0, stream>>>(x, n1w, xn);
    pack_w_kernel<<<4096, 256, 0, stream>>>(Wq_up, Wrot_q, Wk_up, Wrot_k, Wv_up, pq, pk, pv);
    rope_table_kernel<<<(S_ * 16) / 256, 256, 0, stream>>>(cost, sint);
    gemm_kernel<64, 64, false><<<dim3(8, 64, 1), 256, 0, stream>>>(
        xn, Wq_lat, zq, nullptr, T_, D_, D_, LQ_, LQ_, 0, 0);
    gemm_kernel<64, 64, false><<<dim3(4, 64, 1), 256, 0, stream>>>(
        xn, Wkv_lat, zkv, nullptr, T_, D_, D_, LKV_, LKV_, 0, 0);
    gemm_kernel<128, 64, false><<<dim3(1, 32, 16), 256, 0, stream>>>(
        zq, pq, qb, nullptr, T_, LQ_, LQ_, 64, D_, (long long)LQ_ * 64, 64);
    gemm_kernel<128, 64, false><<<dim3(1, 32, 16), 256, 0, stream>>>(
        zkv, pk, kb, nullptr, T_, LKV_, LKV_, 64, D_, (long long)LKV_ * 64, 64);
    gemm_kernel<128, 64, false><<<dim3(1, 32, 16), 256, 0, stream>>>(
        zkv, pv, vb, nullptr, T_, LKV_, LKV_, 64, D_, (long long)LKV_ * 64, 64);
    rope_apply_kernel<<<(T_ * H_) / 256, 256, 0, stream>>>(qb, kb, cost, sint);
    attn_kernel<<<dim3(1024), 256, 0, stream>>>(qb, kb, vb, att);
    gemm_kernel<128, 128, true><<<dim3(8, 32, 1), 256, 0, stream>>>(
        att, Wout, x1, x, T_, D_, D_, D_, D_, 0, 0);

    // --- sublayer 2: MoE ---
    rmsnorm_kernel<<<T_, 256, 0, stream>>>(x1, n2w, xn);                  // xn = xn2 (f32)
    cvt_bf16_kernel<<<(T_ * D_ / 8 + 255) / 256, 256, 0, stream>>>(xn, xnb, T_ * D_ / 8);
    hipMemsetAsync(icnt, 0, T_ * sizeof(int), stream);
    gate_kernel<<<T_, 256, 0, stream>>>(xn, Wgate, ebias, pri);           // fp32 gate
    select_kernel<<<NR_, 1024, 0, stream>>>(pri, seli, selw, icnt, ipr);  // exact top-CAP

    // weight packs (transpose + bf16); xn region free after gate
    packT_kernel<<<dim3(32, 32, 7), 256, 0, stream>>>(Wr2, Wr2T, 1024, 1024, 0,
                                                      (long long)1024 * 1024, (long long)1024 * 1024);
    packT_kernel<<<dim3(32, 64, 1), 256, 0, stream>>>(Ws1, Ws1T, 1024, 2048, 0, 0, 0);
    packT_kernel<<<dim3(32, 32, 1), 256, 0, stream>>>(Ws2, Ws2T, 1024, 1024, 0, 0, 0);

    // routed experts first (Wr1 halves staged through the ATT region)
    packT_kernel<<<dim3(32, 32, 7), 256, 0, stream>>>(Wr1, Wr1H, 1024, 2048, 0,
                                                      (long long)1024 * 2048, (long long)1024 * 1024);
    mfma_gemm_kernel<true, false, true><<<dim3(8, 5, 7), 256, 0, stream>>>(
        xnb, Wr1H, hbuf, seli, nullptr, CAP_, 1024, 1024, 2048,
        0, (long long)1024 * 1024, (long long)CAP_ * 2048, CAP_);
    packT_kernel<<<dim3(32, 32, 7), 256, 0, stream>>>(Wr1, Wr1H, 1024, 2048, 1024,
                                                      (long long)1024 * 2048, (long long)1024 * 1024);
    mfma_gemm_kernel<true, false, true><<<dim3(8, 5, 7), 256, 0, stream>>>(
        xnb, Wr1H, hbuf + 1024, seli, nullptr, CAP_, 1024, 1024, 2048,
        0, (long long)1024 * 1024, (long long)CAP_ * 2048, CAP_);
    swiglu_kernel<<<(NR_ * CAP_ * 128 + 255) / 256, 256, 0, stream>>>(hbuf, actb, NR_ * CAP_);
    mfma_gemm_kernel<false, true, false><<<dim3(8, 5, 7), 256, 0, stream>>>(
        actb, Wr2T, eout, nullptr, selw, CAP_, 1024, 1024, 1024,
        (long long)CAP_ * 1024, (long long)1024 * 1024, (long long)CAP_ * 1024, CAP_);

    // shared expert (ATT region now free -> shout)
    mfma_gemm_kernel<false, false, true><<<dim3(16, 32, 1), 256, 0, stream>>>(
        xnb, Ws1T, hbuf, nullptr, nullptr, T_, 1024, 1024, 2048, 0, 0, 0, 0);
    swiglu_kernel<<<(T_ * 128 + 255) / 256, 256, 0, stream>>>(hbuf, actb, T_);
    mfma_gemm_kernel<false, false, false><<<dim3(8, 32, 1), 256, 0, stream>>>(
        actb, Ws2T, shout, nullptr, nullptr, T_, 1024, 1024, 1024, 0, 0, 0, 0);

    // combine
    final_kernel<<<T_, 256, 0, stream>>>(x1, shout, eout, icnt, ipr, out);
}

// Round 4
// 1193.900 us; speedup vs baseline: 1.9276x; 1.0316x over previous
//
#include <hip/hip_runtime.h>
#include <cstdint>
#include <cstddef>

// ---------------- static problem config ----------------
#define B_   2
#define S_   2048
#define D_   1024
#define T_   4096          // B*S
#define H_   16
#define HD_  64
#define LQ_  512
#define LKV_ 256
#define FF_  1024
#define NR_  7
#define CAP_ 585

typedef unsigned int   u32;
typedef unsigned long long u64;
typedef __bf16 bf16_t;
typedef __bf16 bf16x8 __attribute__((ext_vector_type(8)));
typedef float  f32x4  __attribute__((ext_vector_type(4)));

// ---------------- workspace layout (bytes) ----------------
// fp32 attention path (routing fidelity); bf16 MFMA experts. Regions phase-reused. ~111 MB.
static constexpr size_t MB_ = 1024 * 1024;
static constexpr size_t OFF_XN   = 0;              // [T][D] f32 xn/xn2 (16M) -> MoE: Wr2T bf16 (14.7M)
static constexpr size_t OFF_ZLAT = 16 * MB_;       // [T][768] f32 zq|zkv (12M) -> MoE: xnb bf16 8M + Ws1T 4M
static constexpr size_t OFF_Q    = 28 * MB_;       // [T][1024] f32 q (16M) -> MoE: hbuf bf16 [.][2048]
static constexpr size_t OFF_KV   = 44 * MB_;       // [T][2048] f32 k|v interleaved (32M) -> MoE: actb 8M + eout f32 16.8M
static constexpr size_t OFF_ATT  = 76 * MB_;       // PLAT 3M | PQC 2M | PKV 2M (pre-attn) -> att f32 16M -> Wr1H bf16 -> shout f32
static constexpr size_t OFF_X1   = 92 * MB_;       // [T][D] f32 residual after attention (16M)
static constexpr size_t OFF_PRI  = 108 * MB_;            // [NR][T] f32
static constexpr size_t OFF_SELI = OFF_PRI + 128 * 1024; // [NR][CAP] int
static constexpr size_t OFF_SELW = OFF_SELI + 32 * 1024; // [NR][CAP] f32
static constexpr size_t OFF_ICNT = OFF_SELW + 32 * 1024; // [T] int
static constexpr size_t OFF_IPR  = OFF_ICNT + 32 * 1024; // [T][2] int
static constexpr size_t OFF_COS  = OFF_IPR + 64 * 1024;  // [S][16] f32
static constexpr size_t OFF_SIN  = OFF_COS + 128 * 1024; // [S][16] f32
static constexpr size_t OFF_WS2T = 109 * MB_;            // Ws2T bf16 [1024][1024] (2M) -> ends 111M

static constexpr size_t OFF_PLAT = OFF_ATT;              // [1024][768] f32 (3M)  — dead before attn writes
static constexpr size_t OFF_PQC  = OFF_ATT + 3 * MB_;    // [512][1024] f32 (2M)
static constexpr size_t OFF_PKV  = OFF_ATT + 5 * MB_;    // [256][2048] f32 (2M)

// ---------------- RMSNorm ----------------
__global__ __launch_bounds__(256) void rmsnorm_kernel(const float* __restrict__ x,
                                                      const float* __restrict__ w,
                                                      float* __restrict__ out) {
    int t = blockIdx.x;
    int c = threadIdx.x * 4;
    float4 f = *(const float4*)(x + (size_t)t * D_ + c);
    float ss = f.x * f.x + f.y * f.y + f.z * f.z + f.w * f.w;
#pragma unroll
    for (int off = 32; off > 0; off >>= 1) ss += __shfl_down(ss, off);
    __shared__ float red[4];
    int lane = threadIdx.x & 63, wid = threadIdx.x >> 6;
    if (lane == 0) red[wid] = ss;
    __syncthreads();
    float tot = red[0] + red[1] + red[2] + red[3];
    float inv = 1.f / sqrtf(tot * (1.f / D_) + 1e-6f);
    float4 wv = *(const float4*)(w + c);
    float4 o;
    o.x = f.x * inv * wv.x;
    o.y = f.y * inv * wv.y;
    o.z = f.z * inv * wv.z;
    o.w = f.w * inv * wv.w;
    *(float4*)(out + (size_t)t * D_ + c) = o;
}

// ---------------- pack fp32 attention weights (column layouts for big GEMMs) ----------------
// PLAT[k][c] (c<512: Wq_lat, else Wkv_lat) ; PQC[k][h*64+j] (j<32 cont, j>=32 rot)
// PKV[k][c]  (c<1024: k-weights cont/rot, else: Wv_up)
__global__ __launch_bounds__(256) void pack_w_kernel(const float* __restrict__ Wq_lat, const float* __restrict__ Wkv_lat,
                                                     const float* __restrict__ Wq_up, const float* __restrict__ Wrot_q,
                                                     const float* __restrict__ Wk_up, const float* __restrict__ Wrot_k,
                                                     const float* __restrict__ Wv_up,
                                                     float* __restrict__ PLAT, float* __restrict__ PQC,
                                                     float* __restrict__ PKV) {
    int i = blockIdx.x * 256 + threadIdx.x;
    const int NL = 1024 * 768;
    const int NQ = 512 * 1024;
    if (i < NL) {
        int k = i / 768, c = i - k * 768;
        PLAT[i] = (c < 512) ? Wq_lat[k * 512 + c] : Wkv_lat[k * 256 + (c - 512)];
    } else if (i < NL + NQ) {
        int i2 = i - NL;
        int k = i2 >> 10, c = i2 & 1023, h = c >> 6, j = c & 63;
        PQC[i2] = (j < 32) ? Wq_up[k * 1024 + c] : Wrot_q[k * 1024 + h * 64 + (j - 32)];
    } else {
        int i3 = i - NL - NQ;
        int k = i3 >> 11, c = i3 & 2047;
        if (c < 1024) {
            int h = c >> 6, j = c & 63;
            PKV[i3] = (j < 32) ? Wk_up[k * 1024 + c] : Wrot_k[k * 1024 + h * 64 + (j - 32)];
        } else {
            PKV[i3] = Wv_up[k * 1024 + (c - 1024)];
        }
    }
}

// ---------------- rope tables ----------------
__global__ __launch_bounds__(256) void rope_table_kernel(float* __restrict__ ct, float* __restrict__ st) {
    int i = blockIdx.x * 256 + threadIdx.x;   // S_*16
    if (i >= S_ * 16) return;
    int s = i >> 4, j = i & 15;
    float inv = 1.f / powf(10000.f, (float)j * (1.f / 16.f));
    float fr = (float)s * inv;
    ct[i] = cosf(fr);
    st[i] = sinf(fr);
}

// apply rope in place: q [T][1024], k = cols 0..1023 of kv [T][2048]; rot dims = h*64+32..63
__global__ __launch_bounds__(256) void rope_apply_kernel(float* __restrict__ q, float* __restrict__ kv,
                                                         const float* __restrict__ ct, const float* __restrict__ st) {
    int gid = blockIdx.x * 256 + threadIdx.x;
    if (gid >= T_ * H_) return;
    int t = gid >> 4, h = gid & 15;
    int s = t & (S_ - 1);
    float c[16], sn[16];
#pragma unroll
    for (int j = 0; j < 16; j += 4) {
        *(float4*)&c[j]  = *(const float4*)(ct + s * 16 + j);
        *(float4*)&sn[j] = *(const float4*)(st + s * 16 + j);
    }
#pragma unroll
    for (int a2 = 0; a2 < 2; a2++) {
        float* p = a2 ? (kv + (size_t)t * 2048 + h * 64 + 32)
                      : (q  + (size_t)t * 1024 + h * 64 + 32);
        float r[32], o2[32];
#pragma unroll
        for (int j2 = 0; j2 < 32; j2 += 4) *(float4*)&r[j2] = *(const float4*)(p + j2);
#pragma unroll
        for (int i = 0; i < 16; i++) {
            o2[i]      = r[i] * c[i] - r[i + 16] * sn[i];
            o2[i + 16] = r[i + 16] * c[i] + r[i] * sn[i];
        }
#pragma unroll
        for (int j2 = 0; j2 < 32; j2 += 4) *(float4*)(p + j2) = *(const float4*)&o2[j2];
    }
}

// ---------------- fp32 tiled GEMM 128x128: C = A @ B (+resid) ----------------
template <bool RESID>
__global__ __launch_bounds__(256) void gemm_kernel(const float* __restrict__ A, const float* __restrict__ Bw,
                                                   float* __restrict__ C, const float* __restrict__ resid,
                                                   int K, int lda, int ldb, int ldc) {
    __shared__ float As[16][132];
    __shared__ float Bs[16][128];
    const int tid = threadIdx.x, tx = tid & 15, ty = tid >> 4;
    const int m0 = blockIdx.y * 128, n0 = blockIdx.x * 128;

    float acc[8][8];
#pragma unroll
    for (int m = 0; m < 8; m++)
#pragma unroll
        for (int n = 0; n < 8; n++) acc[m][n] = 0.f;

    for (int k0 = 0; k0 < K; k0 += 16) {
#pragma unroll
        for (int i = 0; i < 2; i++) {
            int id = tid + i * 256;
            int ar = id >> 2, ac = (id & 3) * 4;
            float4 av = *(const float4*)(A + (size_t)(m0 + ar) * lda + k0 + ac);
            As[ac + 0][ar] = av.x; As[ac + 1][ar] = av.y; As[ac + 2][ar] = av.z; As[ac + 3][ar] = av.w;
        }
#pragma unroll
        for (int i = 0; i < 2; i++) {
            int id = tid + i * 256;
            int br = id >> 5, bc = (id & 31) * 4;
            *(float4*)&Bs[br][bc] = *(const float4*)(Bw + (size_t)(k0 + br) * ldb + n0 + bc);
        }
        __syncthreads();
#pragma unroll
        for (int kk = 0; kk < 16; kk++) {
            float a[8], b[8];
            *(float4*)&a[0] = *(const float4*)&As[kk][ty * 8];
            *(float4*)&a[4] = *(const float4*)&As[kk][ty * 8 + 4];
            *(float4*)&b[0] = *(const float4*)&Bs[kk][tx * 8];
            *(float4*)&b[4] = *(const float4*)&Bs[kk][tx * 8 + 4];
#pragma unroll
            for (int m = 0; m < 8; m++)
#pragma unroll
                for (int n = 0; n < 8; n++) acc[m][n] = fmaf(a[m], b[n], acc[m][n]);
        }
        __syncthreads();
    }
#pragma unroll
    for (int m = 0; m < 8; m++) {
        int r = m0 + ty * 8 + m;
#pragma unroll
        for (int n = 0; n < 8; n += 4) {
            int cc = n0 + tx * 8 + n;
            float4 v;
            v.x = acc[m][n + 0]; v.y = acc[m][n + 1]; v.z = acc[m][n + 2]; v.w = acc[m][n + 3];
            if (RESID) {
                float4 rv = *(const float4*)(resid + (size_t)r * ldc + cc);
                v.x += rv.x; v.y += rv.y; v.z += rv.z; v.w += rv.w;
            }
            *(float4*)(C + (size_t)r * ldc + cc) = v;
        }
    }
}

// ---------------- fp32 flash attention (causal), LPT, register softmax, fast exp ----------------
__global__ __launch_bounds__(256) void attn_kernel(const float* __restrict__ Q, const float* __restrict__ KV,
                                                   float* __restrict__ O) {
    __shared__ float Qs[64][68];    // Q transposed: Qs[d][r]
    __shared__ float Ks[64][68];    // K transposed Ks[d][c]; reused as P^T[c][r] after QK
    __shared__ float Vs[64][64];    // natural: Vs[c][d]
    const int tid = threadIdx.x, tx = tid & 15, ty = tid >> 4;
    const int jb = blockIdx.x;
    const int qt = 31 - (jb >> 5);          // LPT: heaviest q-tiles first
    const int bh = jb & 31, b = bh >> 4, h = bh & 15;
    const int q0 = qt * 64;
    const float* Qb = Q  + (size_t)b * S_ * 1024 + h * 64;
    const float* Kb = KV + (size_t)b * S_ * 2048 + h * 64;
    const float* Vb = KV + (size_t)b * S_ * 2048 + 1024 + h * 64;

    for (int idx = tid; idx < 1024; idx += 256) {
        int r = idx >> 4, c4 = (idx & 15) * 4;
        float4 qv = *(const float4*)(Qb + (size_t)(q0 + r) * 1024 + c4);
        Qs[c4 + 0][r] = qv.x; Qs[c4 + 1][r] = qv.y; Qs[c4 + 2][r] = qv.z; Qs[c4 + 3][r] = qv.w;
    }
    float m_r[4], l_r[4], o[4][4];
#pragma unroll
    for (int i = 0; i < 4; i++) {
        m_r[i] = -3.0e38f; l_r[i] = 0.f;
#pragma unroll
        for (int j = 0; j < 4; j++) o[i][j] = 0.f;
    }
    __syncthreads();

    for (int kt = 0; kt <= qt; kt++) {
        int k0 = kt * 64;
        for (int idx = tid; idx < 1024; idx += 256) {
            int r = idx >> 4, c4 = (idx & 15) * 4;
            float4 kv = *(const float4*)(Kb + (size_t)(k0 + r) * 2048 + c4);
            Ks[c4 + 0][r] = kv.x; Ks[c4 + 1][r] = kv.y; Ks[c4 + 2][r] = kv.z; Ks[c4 + 3][r] = kv.w;
            *(float4*)&Vs[r][c4] = *(const float4*)(Vb + (size_t)(k0 + r) * 2048 + c4);
        }
        __syncthreads();
        float s[4][4];
#pragma unroll
        for (int i = 0; i < 4; i++)
#pragma unroll
            for (int j = 0; j < 4; j++) s[i][j] = 0.f;
#pragma unroll 16
        for (int d = 0; d < 64; d++) {
            float a[4], bb[4];
            *(float4*)&a[0]  = *(const float4*)&Qs[d][ty * 4];
            *(float4*)&bb[0] = *(const float4*)&Ks[d][tx * 4];
#pragma unroll
            for (int i = 0; i < 4; i++)
#pragma unroll
                for (int j = 0; j < 4; j++) s[i][j] = fmaf(a[i], bb[j], s[i][j]);
        }
        // scale + causal mask + register/shuffle softmax (row group = 16 lanes sharing ty)
        float e[4][4];
#pragma unroll
        for (int i = 0; i < 4; i++) {
            int qq = q0 + ty * 4 + i;
            float rmax = -3.0e38f;
#pragma unroll
            for (int j = 0; j < 4; j++) {
                int kk2 = k0 + tx * 4 + j;
                float sv = s[i][j] * 0.125f + (kk2 <= qq ? 0.f : -1e9f);
                s[i][j] = sv;
                rmax = fmaxf(rmax, sv);
            }
#pragma unroll
            for (int off = 1; off < 16; off <<= 1) rmax = fmaxf(rmax, __shfl_xor(rmax, off));
            float mn = fmaxf(m_r[i], rmax);
            float al = __expf(m_r[i] - mn);
            m_r[i] = mn;
            float rs = 0.f;
#pragma unroll
            for (int j = 0; j < 4; j++) { float p = __expf(s[i][j] - mn); e[i][j] = p; rs += p; }
#pragma unroll
            for (int off = 1; off < 16; off <<= 1) rs += __shfl_xor(rs, off);
            l_r[i] = l_r[i] * al + rs;
#pragma unroll
            for (int j = 0; j < 4; j++) o[i][j] *= al;
        }
        __syncthreads();   // all waves done reading Ks (QK); safe to overwrite with P^T
#pragma unroll
        for (int j = 0; j < 4; j++) {
            float4 pv; pv.x = e[0][j]; pv.y = e[1][j]; pv.z = e[2][j]; pv.w = e[3][j];
            *(float4*)&Ks[tx * 4 + j][ty * 4] = pv;
        }
#pragma unroll 16
        for (int c = 0; c < 64; c++) {
            float a[4], bb[4];
            *(float4*)&a[0]  = *(const float4*)&Ks[c][ty * 4];   // P^T[c][own rows]
            *(float4*)&bb[0] = *(const float4*)&Vs[c][tx * 4];
#pragma unroll
            for (int i = 0; i < 4; i++)
#pragma unroll
                for (int j = 0; j < 4; j++) o[i][j] = fmaf(a[i], bb[j], o[i][j]);
        }
        __syncthreads();   // before next tile overwrites Ks/Vs
    }
#pragma unroll
    for (int i = 0; i < 4; i++) {
        float inv = 1.f / l_r[i];
        float4 v;
        v.x = o[i][0] * inv; v.y = o[i][1] * inv; v.z = o[i][2] * inv; v.w = o[i][3] * inv;
        *(float4*)(O + (size_t)(b * S_ + q0 + ty * 4 + i) * 1024 + h * 64 + tx * 4) = v;
    }
}

// ---------------- gate: affinities + top-2 membership -> priority [NR][T] ----------------
__global__ __launch_bounds__(256) void gate_kernel(const float* __restrict__ xn2, const float* __restrict__ Wg,
                                                   const float* __restrict__ bias, float* __restrict__ pri) {
    __shared__ float red[256][8];
    int t = blockIdx.x, tid = threadIdx.x;
    float acc[7] = {0.f, 0.f, 0.f, 0.f, 0.f, 0.f, 0.f};
    for (int d = tid; d < D_; d += 256) {
        float xv = xn2[(size_t)t * D_ + d];
        const float* wr = Wg + d * 7;
#pragma unroll
        for (int e = 0; e < 7; e++) acc[e] = fmaf(xv, wr[e], acc[e]);
    }
#pragma unroll
    for (int e = 0; e < 7; e++) red[tid][e] = acc[e];
    __syncthreads();
    for (int s2 = 128; s2 > 0; s2 >>= 1) {
        if (tid < s2) {
#pragma unroll
            for (int e = 0; e < 7; e++) red[tid][e] += red[tid + s2][e];
        }
        __syncthreads();
    }
    if (tid == 0) {
        float a[7];
#pragma unroll
        for (int e = 0; e < 7; e++) a[e] = 1.f / (1.f + expf(-(red[0][e] + bias[e])));
        int e1 = 0;
#pragma unroll
        for (int e = 1; e < 7; e++) if (a[e] > a[e1]) e1 = e;     // strict > : lowest-index tiebreak
        int e2 = -1;
#pragma unroll
        for (int e = 0; e < 7; e++) if (e != e1 && (e2 < 0 || a[e] > a[e2])) e2 = e;
#pragma unroll
        for (int e = 0; e < 7; e++) pri[(size_t)e * T_ + t] = (e == e1 || e == e2) ? a[e] : -1.f;
    }
}

// ---------------- per-expert capacity selection: exact top-585 via bitonic sort ----------------
__global__ __launch_bounds__(1024) void select_kernel(const float* __restrict__ pri, int* __restrict__ sel_idx,
                                                      float* __restrict__ sel_w, int* __restrict__ inv_cnt,
                                                      int* __restrict__ inv_pair) {
    __shared__ u64 keys[T_];
    const int e = blockIdx.x, tid = threadIdx.x;
    for (int i = tid; i < T_; i += 1024) {
        float p = pri[(size_t)e * T_ + i];
        keys[i] = (p > 0.f) ? ((((u64)__float_as_uint(p)) << 32) | (u32)(T_ - 1 - i)) : 0ull;
    }
    __syncthreads();
    for (int k = 2; k <= T_; k <<= 1) {
        for (int j = k >> 1; j > 0; j >>= 1) {
            for (int i = tid; i < T_; i += 1024) {
                int l = i ^ j;
                if (l > i) {
                    u64 a = keys[i], b2 = keys[l];
                    bool asc = (i & k) != 0;
                    if (asc ? (a > b2) : (a < b2)) { keys[i] = b2; keys[l] = a; }
                }
            }
            __syncthreads();
        }
    }
    if (tid < CAP_) {
        u64 kk = keys[tid];
        int tok = 0; float w = 0.f;
        if (kk) {
            tok = T_ - 1 - (int)(kk & 0xFFFFFFFFull);
            w = __uint_as_float((u32)(kk >> 32));
            int pos = atomicAdd(&inv_cnt[tok], 1);
            inv_pair[tok * 2 + pos] = e * CAP_ + tid;
        }
        sel_idx[e * CAP_ + tid] = tok;
        sel_w[e * CAP_ + tid] = w;
    }
}

// ---------------- f32 -> bf16 bulk convert ----------------
__global__ __launch_bounds__(256) void cvt_bf16_kernel(const float* __restrict__ in, bf16_t* __restrict__ out,
                                                       int n8) {
    int i8 = blockIdx.x * 256 + threadIdx.x;
    if (i8 >= n8) return;
    size_t base = (size_t)i8 * 8;
    float4 a = *(const float4*)(in + base);
    float4 b = *(const float4*)(in + base + 4);
    bf16x8 o;
    o[0] = (bf16_t)a.x; o[1] = (bf16_t)a.y; o[2] = (bf16_t)a.z; o[3] = (bf16_t)a.w;
    o[4] = (bf16_t)b.x; o[5] = (bf16_t)b.y; o[6] = (bf16_t)b.z; o[7] = (bf16_t)b.w;
    *(bf16x8*)(out + base) = o;
}

// ---------------- transpose + convert: out[z][n][k] = (bf16) in[z][k][nbase+n] ----------------
__global__ __launch_bounds__(256) void packT_kernel(const float* __restrict__ in, bf16_t* __restrict__ out,
                                                    int K, int N, int nbase,
                                                    long long inStride, long long outStride) {
    __shared__ float tile[32][33];
    const int z = blockIdx.z;
    const int k0 = blockIdx.x * 32, n0 = blockIdx.y * 32;
    const int rr = threadIdx.x >> 5, cc = threadIdx.x & 31;
    const float* inz = in + (size_t)z * inStride;
#pragma unroll
    for (int it = 0; it < 4; it++) {
        int k = k0 + rr + it * 8;
        tile[rr + it * 8][cc] = inz[(size_t)k * N + nbase + n0 + cc];
    }
    __syncthreads();
    bf16_t* outz = out + (size_t)z * outStride;
#pragma unroll
    for (int it = 0; it < 4; it++) {
        int nl = n0 + rr + it * 8;
        outz[(size_t)nl * K + k0 + cc] = (bf16_t)tile[cc][rr + it * 8];
    }
}

// ---------------- bf16 MFMA GEMM: C = gather(A) @ Bt^T (*scale), 128x128 tile, K-step 32 ----------------
template <bool GATHER, bool SCALE, bool OUTBF16>
__global__ __launch_bounds__(256) void mfma_gemm_kernel(const bf16_t* __restrict__ A, const bf16_t* __restrict__ Bt,
                                                        void* __restrict__ Cv,
                                                        const int* __restrict__ gidx, const float* __restrict__ scale,
                                                        int M, int K, int lda, int ldc,
                                                        long long strideA, long long strideBt, long long strideC,
                                                        int gstride) {
    __shared__ __align__(16) bf16_t As[128 * 32];
    __shared__ __align__(16) bf16_t Bs[128 * 32];
    const int tid = threadIdx.x;
    const int lane = tid & 63, w = tid >> 6;
    const int wm = (w & 1) * 64, wn = (w >> 1) * 64;
    const int z = blockIdx.z;
    const int m0 = blockIdx.y * 128, n0 = blockIdx.x * 128;
    const bf16_t* Az = A + (GATHER ? 0 : (size_t)z * strideA);
    const bf16_t* Bz = Bt + (size_t)z * strideBt;

    int arow[2];
#pragma unroll
    for (int i = 0; i < 2; i++) {
        int chunk = tid + i * 256;
        int r = m0 + (chunk >> 2);
        if (r > M - 1) r = M - 1;
        arow[i] = GATHER ? gidx[z * gstride + r] : r;
    }

    f32x4 acc[4][4];
#pragma unroll
    for (int mi = 0; mi < 4; mi++)
#pragma unroll
        for (int ni = 0; ni < 4; ni++) { f32x4 zz = {0.f, 0.f, 0.f, 0.f}; acc[mi][ni] = zz; }

    const int mrow = lane & 15, q = lane >> 4;
    for (int k0 = 0; k0 < K; k0 += 32) {
#pragma unroll
        for (int i = 0; i < 2; i++) {
            int chunk = tid + i * 256;
            int row = chunk >> 2, koff = (chunk & 3) * 8;
            *(uint4*)(As + row * 32 + koff) = *(const uint4*)(Az + (size_t)arow[i] * lda + k0 + koff);
            *(uint4*)(Bs + row * 32 + koff) = *(const uint4*)(Bz + (size_t)(n0 + row) * K + k0 + koff);
        }
        __syncthreads();
        bf16x8 af[4], bfr[4];
#pragma unroll
        for (int mi = 0; mi < 4; mi++)
            af[mi] = *(const bf16x8*)(As + (wm + mi * 16 + mrow) * 32 + q * 8);
#pragma unroll
        for (int ni = 0; ni < 4; ni++)
            bfr[ni] = *(const bf16x8*)(Bs + (wn + ni * 16 + mrow) * 32 + q * 8);
#pragma unroll
        for (int mi = 0; mi < 4; mi++)
#pragma unroll
            for (int ni = 0; ni < 4; ni++)
                acc[mi][ni] = __builtin_amdgcn_mfma_f32_16x16x32_bf16(af[mi], bfr[ni], acc[mi][ni], 0, 0, 0);
        __syncthreads();
    }
    // epilogue: C/D layout col = lane&15, row = (lane>>4)*4 + v
#pragma unroll
    for (int mi = 0; mi < 4; mi++) {
        int rbase = m0 + wm + mi * 16 + q * 4;
#pragma unroll
        for (int v = 0; v < 4; v++) {
            int r = rbase + v;
            if (r < M) {
                float sc = SCALE ? scale[z * gstride + r] : 1.f;
#pragma unroll
                for (int ni = 0; ni < 4; ni++) {
                    int c = n0 + wn + ni * 16 + mrow;
                    float val = acc[mi][ni][v];
                    if (SCALE) val *= sc;
                    size_t off = (size_t)z * strideC + (size_t)r * ldc + c;
                    if (OUTBF16) ((bf16_t*)Cv)[off] = (bf16_t)val;
                    else         ((float*)Cv)[off] = val;
                }
            }
        }
    }
}

// ---------------- SwiGLU elementwise: act[r][f] = h1 * silu(h2), h = [rows][2048] bf16 ----------------
__global__ __launch_bounds__(256) void swiglu_kernel(const bf16_t* __restrict__ h, bf16_t* __restrict__ act,
                                                     int rows) {
    int i8 = blockIdx.x * 256 + threadIdx.x;
    int total = rows * 128;
    if (i8 >= total) return;
    int r = i8 >> 7, f = (i8 & 127) * 8;
    bf16x8 h1 = *(const bf16x8*)(h + (size_t)r * 2048 + f);
    bf16x8 h2 = *(const bf16x8*)(h + (size_t)r * 2048 + 1024 + f);
    bf16x8 o;
#pragma unroll
    for (int j = 0; j < 8; j++) {
        float a = (float)h1[j], g = (float)h2[j];
        o[j] = (bf16_t)(a * g / (1.f + __expf(-g)));
    }
    *(bf16x8*)(act + (size_t)r * 1024 + f) = o;
}

// ---------------- final combine: out = x1 + shared + sum routed ----------------
__global__ __launch_bounds__(256) void final_kernel(const float* __restrict__ x1, const float* __restrict__ sh,
                                                    const float* __restrict__ eout, const int* __restrict__ icnt,
                                                    const int* __restrict__ ipair, float* __restrict__ out) {
    int t = blockIdx.x, c = threadIdx.x * 4;
    float4 v = *(const float4*)(x1 + (size_t)t * D_ + c);
    float4 s2 = *(const float4*)(sh + (size_t)t * D_ + c);
    v.x += s2.x; v.y += s2.y; v.z += s2.z; v.w += s2.w;
    int n = icnt[t];
    for (int p = 0; p < n; p++) {
        int row = ipair[t * 2 + p];
        float4 ev = *(const float4*)(eout + (size_t)row * D_ + c);
        v.x += ev.x; v.y += ev.y; v.z += ev.z; v.w += ev.w;
    }
    *(float4*)(out + (size_t)t * D_ + c) = v;
}

// ---------------- launch ----------------
extern "C" void kernel_launch(void* const* d_in, const int* in_sizes, int n_in,
                              void* d_out, int out_size, void* d_ws, size_t ws_size,
                              hipStream_t stream) {
    (void)in_sizes; (void)n_in; (void)out_size; (void)ws_size;
    const float* x       = (const float*)d_in[0];
    const float* Wq_lat  = (const float*)d_in[2];
    const float* Wkv_lat = (const float*)d_in[3];
    const float* Wrot_q  = (const float*)d_in[4];
    const float* Wrot_k  = (const float*)d_in[5];
    const float* Wq_up   = (const float*)d_in[6];
    const float* Wk_up   = (const float*)d_in[7];
    const float* Wv_up   = (const float*)d_in[8];
    const float* Wout    = (const float*)d_in[9];
    const float* n1w     = (const float*)d_in[10];
    const float* n2w     = (const float*)d_in[11];
    const float* Ws1     = (const float*)d_in[12];
    const float* Ws2     = (const float*)d_in[13];
    const float* Wr1     = (const float*)d_in[14];
    const float* Wr2     = (const float*)d_in[15];
    const float* Wgate   = (const float*)d_in[16];
    const float* ebias   = (const float*)d_in[17];
    float* out = (float*)d_out;

    char* wsb = (char*)d_ws;
    float* xn    = (float*)(wsb + OFF_XN);
    float* zlat  = (float*)(wsb + OFF_ZLAT);    // [T][768]: cols 0-511 zq, 512-767 zkv
    float* qb    = (float*)(wsb + OFF_Q);       // [T][1024]
    float* kvb   = (float*)(wsb + OFF_KV);      // [T][2048]: cols 0-1023 k, 1024-2047 v
    float* att   = (float*)(wsb + OFF_ATT);
    float* x1    = (float*)(wsb + OFF_X1);
    float* pri   = (float*)(wsb + OFF_PRI);
    int*   seli  = (int*)(wsb + OFF_SELI);
    float* selw  = (float*)(wsb + OFF_SELW);
    int*   icnt  = (int*)(wsb + OFF_ICNT);
    int*   ipr   = (int*)(wsb + OFF_IPR);
    float* cost  = (float*)(wsb + OFF_COS);
    float* sint  = (float*)(wsb + OFF_SIN);
    float* plat  = (float*)(wsb + OFF_PLAT);
    float* pqc   = (float*)(wsb + OFF_PQC);
    float* pkv   = (float*)(wsb + OFF_PKV);
    // MoE-phase aliases (reuse of dead regions)
    bf16_t* Wr2T = (bf16_t*)(wsb + OFF_XN);           // [7][1024][1024] bf16 (14.7M <= 16M)
    bf16_t* xnb  = (bf16_t*)(wsb + OFF_ZLAT);         // [T][1024] bf16 (8M)
    bf16_t* Ws1T = (bf16_t*)(wsb + OFF_ZLAT + 8 * MB_); // [2048][1024] bf16 (4M <= remaining 4M)
    bf16_t* hbuf = (bf16_t*)(wsb + OFF_Q);            // [rows][2048] bf16 (<=16M)
    bf16_t* actb = (bf16_t*)(wsb + OFF_KV);           // [rows][1024] bf16 (<=8M)
    float*  eout = (float*)(wsb + OFF_KV + 8 * MB_);  // [7*585][1024] f32 (16.8M <= 24M)
    bf16_t* Wr1H = (bf16_t*)(wsb + OFF_ATT);          // [7][1024][1024] bf16 (att dead)
    float*  shout = (float*)(wsb + OFF_ATT);          // [T][1024] f32 (after Wr1H dead)
    bf16_t* Ws2T = (bf16_t*)(wsb + OFF_WS2T);         // [1024][1024] bf16 (2M)

    // --- sublayer 1: attention path, all fp32 (routing fidelity) ---
    rmsnorm_kernel<<<T_, 256, 0, stream>>>(x, n1w, xn);
    pack_w_kernel<<<7168, 256, 0, stream>>>(Wq_lat, Wkv_lat, Wq_up, Wrot_q, Wk_up, Wrot_k, Wv_up,
                                            plat, pqc, pkv);
    rope_table_kernel<<<(S_ * 16) / 256, 256, 0, stream>>>(cost, sint);
    // zlat = xn @ PLAT : 4096x768x1024
    gemm_kernel<false><<<dim3(6, 32), 256, 0, stream>>>(xn, plat, zlat, nullptr, 1024, 1024, 768, 768);
    // q = zlat[:, :512] @ PQC : 4096x1024x512
    gemm_kernel<false><<<dim3(8, 32), 256, 0, stream>>>(zlat, pqc, qb, nullptr, 512, 768, 1024, 1024);
    // k|v = zlat[:, 512:768] @ PKV : 4096x2048x256
    gemm_kernel<false><<<dim3(16, 32), 256, 0, stream>>>(zlat + 512, pkv, kvb, nullptr, 256, 768, 2048, 2048);
    rope_apply_kernel<<<(T_ * H_) / 256, 256, 0, stream>>>(qb, kvb, cost, sint);
    attn_kernel<<<dim3(1024), 256, 0, stream>>>(qb, kvb, att);
    gemm_kernel<true><<<dim3(8, 32), 256, 0, stream>>>(att, Wout, x1, x, 1024, 1024, 1024, 1024);

    // --- sublayer 2: MoE ---
    rmsnorm_kernel<<<T_, 256, 0, stream>>>(x1, n2w, xn);                  // xn = xn2 (f32)
    cvt_bf16_kernel<<<(T_ * D_ / 8 + 255) / 256, 256, 0, stream>>>(xn, xnb, T_ * D_ / 8);
    hipMemsetAsync(icnt, 0, T_ * sizeof(int), stream);
    gate_kernel<<<T_, 256, 0, stream>>>(xn, Wgate, ebias, pri);           // fp32 gate
    select_kernel<<<NR_, 1024, 0, stream>>>(pri, seli, selw, icnt, ipr);  // exact top-CAP

    // weight packs (transpose + bf16); XN region free after gate+cvt
    packT_kernel<<<dim3(32, 32, 7), 256, 0, stream>>>(Wr2, Wr2T, 1024, 1024, 0,
                                                      (long long)1024 * 1024, (long long)1024 * 1024);
    packT_kernel<<<dim3(32, 64, 1), 256, 0, stream>>>(Ws1, Ws1T, 1024, 2048, 0, 0, 0);
    packT_kernel<<<dim3(32, 32, 1), 256, 0, stream>>>(Ws2, Ws2T, 1024, 1024, 0, 0, 0);

    // routed experts first (Wr1 halves staged through the ATT region)
    packT_kernel<<<dim3(32, 32, 7), 256, 0, stream>>>(Wr1, Wr1H, 1024, 2048, 0,
                                                      (long long)1024 * 2048, (long long)1024 * 1024);
    mfma_gemm_kernel<true, false, true><<<dim3(8, 5, 7), 256, 0, stream>>>(
        xnb, Wr1H, hbuf, seli, nullptr, CAP_, 1024, 1024, 2048,
        0, (long long)1024 * 1024, (long long)CAP_ * 2048, CAP_);
    packT_kernel<<<dim3(32, 32, 7), 256, 0, stream>>>(Wr1, Wr1H, 1024, 2048, 1024,
                                                      (long long)1024 * 2048, (long long)1024 * 1024);
    mfma_gemm_kernel<true, false, true><<<dim3(8, 5, 7), 256, 0, stream>>>(
        xnb, Wr1H, hbuf + 1024, seli, nullptr, CAP_, 1024, 1024, 2048,
        0, (long long)1024 * 1024, (long long)CAP_ * 2048, CAP_);
    swiglu_kernel<<<(NR_ * CAP_ * 128 + 255) / 256, 256, 0, stream>>>(hbuf, actb, NR_ * CAP_);
    mfma_gemm_kernel<false, true, false><<<dim3(8, 5, 7), 256, 0, stream>>>(
        actb, Wr2T, eout, nullptr, selw, CAP_, 1024, 1024, 1024,
        (long long)CAP_ * 1024, (long long)1024 * 1024, (long long)CAP_ * 1024, CAP_);

    // shared expert (ATT region now free -> shout)
    mfma_gemm_kernel<false, false, true><<<dim3(16, 32, 1), 256, 0, stream>>>(
        xnb, Ws1T, hbuf, nullptr, nullptr, T_, 1024, 1024, 2048, 0, 0, 0, 0);
    swiglu_kernel<<<(T_ * 128 + 255) / 256, 256, 0, stream>>>(hbuf, actb, T_);
    mfma_gemm_kernel<false, false, false><<<dim3(8, 32, 1), 256, 0, stream>>>(
        actb, Ws2T, shout, nullptr, nullptr, T_, 1024, 1024, 1024, 0, 0, 0, 0);

    // combine
    final_kernel<<<T_, 256, 0, stream>>>(x1, shout, eout, icnt, ipr, out);
}

// Round 6
// 998.328 us; speedup vs baseline: 2.3052x; 1.1959x over previous
//
#include <hip/hip_runtime.h>
#include <cstdint>
#include <cstddef>

// ---------------- static problem config ----------------
#define B_   2
#define S_   2048
#define D_   1024
#define T_   4096          // B*S
#define H_   16
#define HD_  64
#define LQ_  512
#define LKV_ 256
#define FF_  1024
#define NR_  7
#define CAP_ 585

typedef unsigned int   u32;
typedef unsigned long long u64;
typedef __bf16 bf16_t;
typedef __bf16 bf16x8 __attribute__((ext_vector_type(8)));
typedef __bf16 bf16x4 __attribute__((ext_vector_type(4)));
typedef float  f32x4  __attribute__((ext_vector_type(4)));

// ---------------- workspace layout (bytes), regions phase-reused, ~111 MB ----------------
static constexpr size_t MB_ = 1024 * 1024;
static constexpr size_t KB_ = 1024;
// R0 0-16M: xn hi(8M)+lo(8M) -> att hi+lo -> xn2 f32 -> Wr2T bf16 (14.7M)
static constexpr size_t OFF_R0   = 0;
// R1 16-28M: zlat hi(6M)+lo(6M) -> xnb bf16 8M + Ws1T 4M
static constexpr size_t OFF_R1   = 16 * MB_;
// R2 28-44M: PLAT/PQC/PKV f32 temps (7M) -> q f32 16M -> hbuf bf16 16M
static constexpr size_t OFF_R2   = 28 * MB_;
// R3 44-76M: kv f32 32M -> actb bf16 8M + eout f32 16.8M
static constexpr size_t OFF_R3   = 44 * MB_;
// R4 76-92M: weight splits (11M) -> Wr1H bf16 14.7M -> shout f32 16M
static constexpr size_t OFF_R4   = 76 * MB_;
static constexpr size_t OFF_X1   = 92 * MB_;             // [T][D] f32
static constexpr size_t OFF_PRI  = 108 * MB_;            // [NR][T] f32 (128K)
static constexpr size_t OFF_SELI = OFF_PRI + 128 * KB_;  // [NR][CAP] int
static constexpr size_t OFF_SELW = OFF_SELI + 32 * KB_;  // [NR][CAP] f32
static constexpr size_t OFF_ICNT = OFF_SELW + 32 * KB_;  // [T] int
static constexpr size_t OFF_IPR  = OFF_ICNT + 32 * KB_;  // [T][2] int
static constexpr size_t OFF_COS  = OFF_IPR + 64 * KB_;   // [S][16] f32
static constexpr size_t OFF_SIN  = OFF_COS + 128 * KB_;  // [S][16] f32
static constexpr size_t OFF_WS2T = 109 * MB_;            // Ws2T bf16 2M -> ends 111M
// sub-offsets
static constexpr size_t OFF_PLAT = OFF_R2;               // [1024][768] f32 (3M)
static constexpr size_t OFF_PQC  = OFF_R2 + 3 * MB_;     // [512][1024] f32 (2M)
static constexpr size_t OFF_PKV  = OFF_R2 + 5 * MB_;     // [256][2048] f32 (2M)
static constexpr size_t OFF_PLTH = OFF_R4;                    // PLATT hi [768][1024] (1.5M)
static constexpr size_t OFF_PLTL = OFF_R4 + 1536 * KB_;       // lo
static constexpr size_t OFF_PQTH = OFF_R4 + 3 * MB_;          // PQCT hi [1024][512] (1M)
static constexpr size_t OFF_PQTL = OFF_R4 + 4 * MB_;
static constexpr size_t OFF_PKTH = OFF_R4 + 5 * MB_;          // PKVT hi [2048][256] (1M)
static constexpr size_t OFF_PKTL = OFF_R4 + 6 * MB_;
static constexpr size_t OFF_WOTH = OFF_R4 + 7 * MB_;          // WoutT hi [1024][1024] (2M)
static constexpr size_t OFF_WOTL = OFF_R4 + 9 * MB_;

__device__ __forceinline__ void split2(float v, bf16_t& h, bf16_t& l) {
    h = (bf16_t)v;
    l = (bf16_t)(v - (float)h);
}

// ---------------- RMSNorm: MODE 0 -> emit hi/lo bf16 planes; MODE 1 -> emit f32 + single bf16 ----------------
template <int MODE>
__global__ __launch_bounds__(256) void rmsnorm_kernel(const float* __restrict__ x,
                                                      const float* __restrict__ w,
                                                      float* __restrict__ outf,
                                                      bf16_t* __restrict__ o1,
                                                      bf16_t* __restrict__ o2) {
    int t = blockIdx.x;
    int c = threadIdx.x * 4;
    float4 f = *(const float4*)(x + (size_t)t * D_ + c);
    float ss = f.x * f.x + f.y * f.y + f.z * f.z + f.w * f.w;
#pragma unroll
    for (int off = 32; off > 0; off >>= 1) ss += __shfl_down(ss, off);
    __shared__ float red[4];
    int lane = threadIdx.x & 63, wid = threadIdx.x >> 6;
    if (lane == 0) red[wid] = ss;
    __syncthreads();
    float tot = red[0] + red[1] + red[2] + red[3];
    float inv = 1.f / sqrtf(tot * (1.f / D_) + 1e-6f);
    float4 wv = *(const float4*)(w + c);
    float v[4];
    v[0] = f.x * inv * wv.x; v[1] = f.y * inv * wv.y;
    v[2] = f.z * inv * wv.z; v[3] = f.w * inv * wv.w;
    if (MODE == 0) {
        bf16x4 hv, lv;
#pragma unroll
        for (int j = 0; j < 4; j++) { bf16_t h, l; split2(v[j], h, l); hv[j] = h; lv[j] = l; }
        *(bf16x4*)(o1 + (size_t)t * D_ + c) = hv;
        *(bf16x4*)(o2 + (size_t)t * D_ + c) = lv;
    } else {
        float4 o; o.x = v[0]; o.y = v[1]; o.z = v[2]; o.w = v[3];
        *(float4*)(outf + (size_t)t * D_ + c) = o;
        bf16x4 bv;
#pragma unroll
        for (int j = 0; j < 4; j++) bv[j] = (bf16_t)v[j];
        *(bf16x4*)(o1 + (size_t)t * D_ + c) = bv;
    }
}

// ---------------- pack fp32 attention weights into [K][N] fused layouts ----------------
__global__ __launch_bounds__(256) void pack_w_kernel(const float* __restrict__ Wq_lat, const float* __restrict__ Wkv_lat,
                                                     const float* __restrict__ Wq_up, const float* __restrict__ Wrot_q,
                                                     const float* __restrict__ Wk_up, const float* __restrict__ Wrot_k,
                                                     const float* __restrict__ Wv_up,
                                                     float* __restrict__ PLAT, float* __restrict__ PQC,
                                                     float* __restrict__ PKV) {
    int i = blockIdx.x * 256 + threadIdx.x;
    const int NL = 1024 * 768;
    const int NQ = 512 * 1024;
    if (i < NL) {
        int k = i / 768, c = i - k * 768;
        PLAT[i] = (c < 512) ? Wq_lat[k * 512 + c] : Wkv_lat[k * 256 + (c - 512)];
    } else if (i < NL + NQ) {
        int i2 = i - NL;
        int k = i2 >> 10, c = i2 & 1023, h = c >> 6, j = c & 63;
        PQC[i2] = (j < 32) ? Wq_up[k * 1024 + c] : Wrot_q[k * 1024 + h * 64 + (j - 32)];
    } else {
        int i3 = i - NL - NQ;
        int k = i3 >> 11, c = i3 & 2047;
        if (c < 1024) {
            int h = c >> 6, j = c & 63;
            PKV[i3] = (j < 32) ? Wk_up[k * 1024 + c] : Wrot_k[k * 1024 + h * 64 + (j - 32)];
        } else {
            PKV[i3] = Wv_up[k * 1024 + (c - 1024)];
        }
    }
}

// ---------------- transpose + split: in [K][N] f32 -> outhi/outlo [N][K] bf16 ----------------
__global__ __launch_bounds__(256) void packTsplit_kernel(const float* __restrict__ in,
                                                         bf16_t* __restrict__ outhi, bf16_t* __restrict__ outlo,
                                                         int K, int N) {
    __shared__ float tile[32][33];
    const int k0 = blockIdx.x * 32, n0 = blockIdx.y * 32;
    const int rr = threadIdx.x >> 5, cc = threadIdx.x & 31;
#pragma unroll
    for (int it = 0; it < 4; it++) {
        int k = k0 + rr + it * 8;
        tile[rr + it * 8][cc] = in[(size_t)k * N + n0 + cc];
    }
    __syncthreads();
#pragma unroll
    for (int it = 0; it < 4; it++) {
        int nl = n0 + rr + it * 8;
        float v = tile[cc][rr + it * 8];
        bf16_t h, l; split2(v, h, l);
        outhi[(size_t)nl * K + k0 + cc] = h;
        outlo[(size_t)nl * K + k0 + cc] = l;
    }
}

// ---------------- rope tables ----------------
__global__ __launch_bounds__(256) void rope_table_kernel(float* __restrict__ ct, float* __restrict__ st) {
    int i = blockIdx.x * 256 + threadIdx.x;   // S_*16
    if (i >= S_ * 16) return;
    int s = i >> 4, j = i & 15;
    float inv = 1.f / powf(10000.f, (float)j * (1.f / 16.f));
    float fr = (float)s * inv;
    ct[i] = cosf(fr);
    st[i] = sinf(fr);
}

// apply rope in place: q [T][1024], k = cols 0..1023 of kv [T][2048]; rot dims = h*64+32..63
__global__ __launch_bounds__(256) void rope_apply_kernel(float* __restrict__ q, float* __restrict__ kv,
                                                         const float* __restrict__ ct, const float* __restrict__ st) {
    int gid = blockIdx.x * 256 + threadIdx.x;
    if (gid >= T_ * H_) return;
    int t = gid >> 4, h = gid & 15;
    int s = t & (S_ - 1);
    float c[16], sn[16];
#pragma unroll
    for (int j = 0; j < 16; j += 4) {
        *(float4*)&c[j]  = *(const float4*)(ct + s * 16 + j);
        *(float4*)&sn[j] = *(const float4*)(st + s * 16 + j);
    }
#pragma unroll
    for (int a2 = 0; a2 < 2; a2++) {
        float* p = a2 ? (kv + (size_t)t * 2048 + h * 64 + 32)
                      : (q  + (size_t)t * 1024 + h * 64 + 32);
        float r[32], o2[32];
#pragma unroll
        for (int j2 = 0; j2 < 32; j2 += 4) *(float4*)&r[j2] = *(const float4*)(p + j2);
#pragma unroll
        for (int i = 0; i < 16; i++) {
            o2[i]      = r[i] * c[i] - r[i + 16] * sn[i];
            o2[i + 16] = r[i + 16] * c[i] + r[i] * sn[i];
        }
#pragma unroll
        for (int j2 = 0; j2 < 32; j2 += 4) *(float4*)(p + j2) = *(const float4*)&o2[j2];
    }
}

// ---------------- bf16x3 MFMA GEMM (near-fp32): C = (Ah+Al)@(Bh+Bl)^T (+resid) ----------------
// M fixed = 4096 (full rows). EMIT: 0 = f32 out, 1 = hi/lo split out.
template <bool RESID, int EMIT>
__global__ __launch_bounds__(256) void mfma3_gemm_kernel(const bf16_t* __restrict__ Ah, const bf16_t* __restrict__ Al,
                                                         const bf16_t* __restrict__ Bh, const bf16_t* __restrict__ Bl,
                                                         float* __restrict__ Cf,
                                                         bf16_t* __restrict__ Chi, bf16_t* __restrict__ Clo,
                                                         const float* __restrict__ resid,
                                                         int K, int lda, int ldc) {
    __shared__ __align__(16) bf16_t Ash[128 * 32];
    __shared__ __align__(16) bf16_t Asl[128 * 32];
    __shared__ __align__(16) bf16_t Bsh[128 * 32];
    __shared__ __align__(16) bf16_t Bsl[128 * 32];
    const int tid = threadIdx.x;
    const int lane = tid & 63, w = tid >> 6;
    const int wm = (w & 1) * 64, wn = (w >> 1) * 64;
    const int m0 = blockIdx.y * 128, n0 = blockIdx.x * 128;

    f32x4 acc[4][4];
#pragma unroll
    for (int mi = 0; mi < 4; mi++)
#pragma unroll
        for (int ni = 0; ni < 4; ni++) { f32x4 zz = {0.f, 0.f, 0.f, 0.f}; acc[mi][ni] = zz; }

    const int mrow = lane & 15, q = lane >> 4;
    for (int k0 = 0; k0 < K; k0 += 32) {
#pragma unroll
        for (int i = 0; i < 2; i++) {
            int chunk = tid + i * 256;
            int row = chunk >> 2, koff = (chunk & 3) * 8;
            size_t aoff = (size_t)(m0 + row) * lda + k0 + koff;
            size_t boff = (size_t)(n0 + row) * K + k0 + koff;
            *(uint4*)(Ash + row * 32 + koff) = *(const uint4*)(Ah + aoff);
            *(uint4*)(Asl + row * 32 + koff) = *(const uint4*)(Al + aoff);
            *(uint4*)(Bsh + row * 32 + koff) = *(const uint4*)(Bh + boff);
            *(uint4*)(Bsl + row * 32 + koff) = *(const uint4*)(Bl + boff);
        }
        __syncthreads();
        bf16x8 ah[4], al[4], bh[4], bl[4];
#pragma unroll
        for (int mi = 0; mi < 4; mi++) {
            ah[mi] = *(const bf16x8*)(Ash + (wm + mi * 16 + mrow) * 32 + q * 8);
            al[mi] = *(const bf16x8*)(Asl + (wm + mi * 16 + mrow) * 32 + q * 8);
        }
#pragma unroll
        for (int ni = 0; ni < 4; ni++) {
            bh[ni] = *(const bf16x8*)(Bsh + (wn + ni * 16 + mrow) * 32 + q * 8);
            bl[ni] = *(const bf16x8*)(Bsl + (wn + ni * 16 + mrow) * 32 + q * 8);
        }
#pragma unroll
        for (int mi = 0; mi < 4; mi++)
#pragma unroll
            for (int ni = 0; ni < 4; ni++) {
                acc[mi][ni] = __builtin_amdgcn_mfma_f32_16x16x32_bf16(al[mi], bh[ni], acc[mi][ni], 0, 0, 0);
                acc[mi][ni] = __builtin_amdgcn_mfma_f32_16x16x32_bf16(ah[mi], bl[ni], acc[mi][ni], 0, 0, 0);
                acc[mi][ni] = __builtin_amdgcn_mfma_f32_16x16x32_bf16(ah[mi], bh[ni], acc[mi][ni], 0, 0, 0);
            }
        __syncthreads();
    }
    // epilogue: C/D layout col = lane&15, row = (lane>>4)*4 + v
#pragma unroll
    for (int mi = 0; mi < 4; mi++) {
        int rbase = m0 + wm + mi * 16 + q * 4;
#pragma unroll
        for (int v = 0; v < 4; v++) {
            int r = rbase + v;
#pragma unroll
            for (int ni = 0; ni < 4; ni++) {
                int c = n0 + wn + ni * 16 + mrow;
                float val = acc[mi][ni][v];
                if (RESID) val += resid[(size_t)r * ldc + c];
                if (EMIT == 0) {
                    Cf[(size_t)r * ldc + c] = val;
                } else {
                    bf16_t h, l; split2(val, h, l);
                    Chi[(size_t)r * ldc + c] = h;
                    Clo[(size_t)r * ldc + c] = l;
                }
            }
        }
    }
}

// ---------------- fp32 flash attention (causal), LPT, register softmax; emits hi/lo splits ----------------
__global__ __launch_bounds__(256) void attn_kernel(const float* __restrict__ Q, const float* __restrict__ KV,
                                                   bf16_t* __restrict__ Ohi, bf16_t* __restrict__ Olo) {
    __shared__ float Qs[64][68];    // Q transposed: Qs[d][r]
    __shared__ float Ks[64][68];    // K transposed Ks[d][c]; reused as P^T[c][r] after QK
    __shared__ float Vs[64][64];    // natural: Vs[c][d]
    const int tid = threadIdx.x, tx = tid & 15, ty = tid >> 4;
    const int jb = blockIdx.x;
    const int qt = 31 - (jb >> 5);          // LPT: heaviest q-tiles first
    const int bh = jb & 31, b = bh >> 4, h = bh & 15;
    const int q0 = qt * 64;
    const float* Qb = Q  + (size_t)b * S_ * 1024 + h * 64;
    const float* Kb = KV + (size_t)b * S_ * 2048 + h * 64;
    const float* Vb = KV + (size_t)b * S_ * 2048 + 1024 + h * 64;

    for (int idx = tid; idx < 1024; idx += 256) {
        int r = idx >> 4, c4 = (idx & 15) * 4;
        float4 qv = *(const float4*)(Qb + (size_t)(q0 + r) * 1024 + c4);
        Qs[c4 + 0][r] = qv.x; Qs[c4 + 1][r] = qv.y; Qs[c4 + 2][r] = qv.z; Qs[c4 + 3][r] = qv.w;
    }
    float m_r[4], l_r[4], o[4][4];
#pragma unroll
    for (int i = 0; i < 4; i++) {
        m_r[i] = -3.0e38f; l_r[i] = 0.f;
#pragma unroll
        for (int j = 0; j < 4; j++) o[i][j] = 0.f;
    }
    __syncthreads();

    for (int kt = 0; kt <= qt; kt++) {
        int k0 = kt * 64;
        for (int idx = tid; idx < 1024; idx += 256) {
            int r = idx >> 4, c4 = (idx & 15) * 4;
            float4 kv = *(const float4*)(Kb + (size_t)(k0 + r) * 2048 + c4);
            Ks[c4 + 0][r] = kv.x; Ks[c4 + 1][r] = kv.y; Ks[c4 + 2][r] = kv.z; Ks[c4 + 3][r] = kv.w;
            *(float4*)&Vs[r][c4] = *(const float4*)(Vb + (size_t)(k0 + r) * 2048 + c4);
        }
        __syncthreads();
        float s[4][4];
#pragma unroll
        for (int i = 0; i < 4; i++)
#pragma unroll
            for (int j = 0; j < 4; j++) s[i][j] = 0.f;
#pragma unroll 16
        for (int d = 0; d < 64; d++) {
            float a[4], bb[4];
            *(float4*)&a[0]  = *(const float4*)&Qs[d][ty * 4];
            *(float4*)&bb[0] = *(const float4*)&Ks[d][tx * 4];
#pragma unroll
            for (int i = 0; i < 4; i++)
#pragma unroll
                for (int j = 0; j < 4; j++) s[i][j] = fmaf(a[i], bb[j], s[i][j]);
        }
        float e[4][4];
#pragma unroll
        for (int i = 0; i < 4; i++) {
            int qq = q0 + ty * 4 + i;
            float rmax = -3.0e38f;
#pragma unroll
            for (int j = 0; j < 4; j++) {
                int kk2 = k0 + tx * 4 + j;
                float sv = s[i][j] * 0.125f + (kk2 <= qq ? 0.f : -1e9f);
                s[i][j] = sv;
                rmax = fmaxf(rmax, sv);
            }
#pragma unroll
            for (int off = 1; off < 16; off <<= 1) rmax = fmaxf(rmax, __shfl_xor(rmax, off));
            float mn = fmaxf(m_r[i], rmax);
            float al = __expf(m_r[i] - mn);
            m_r[i] = mn;
            float rs = 0.f;
#pragma unroll
            for (int j = 0; j < 4; j++) { float p = __expf(s[i][j] - mn); e[i][j] = p; rs += p; }
#pragma unroll
            for (int off = 1; off < 16; off <<= 1) rs += __shfl_xor(rs, off);
            l_r[i] = l_r[i] * al + rs;
#pragma unroll
            for (int j = 0; j < 4; j++) o[i][j] *= al;
        }
        __syncthreads();   // all waves done reading Ks (QK)
#pragma unroll
        for (int j = 0; j < 4; j++) {
            float4 pv; pv.x = e[0][j]; pv.y = e[1][j]; pv.z = e[2][j]; pv.w = e[3][j];
            *(float4*)&Ks[tx * 4 + j][ty * 4] = pv;
        }
#pragma unroll 16
        for (int c = 0; c < 64; c++) {
            float a[4], bb[4];
            *(float4*)&a[0]  = *(const float4*)&Ks[c][ty * 4];
            *(float4*)&bb[0] = *(const float4*)&Vs[c][tx * 4];
#pragma unroll
            for (int i = 0; i < 4; i++)
#pragma unroll
                for (int j = 0; j < 4; j++) o[i][j] = fmaf(a[i], bb[j], o[i][j]);
        }
        __syncthreads();
    }
#pragma unroll
    for (int i = 0; i < 4; i++) {
        float inv = 1.f / l_r[i];
        bf16x4 hv, lv;
#pragma unroll
        for (int j = 0; j < 4; j++) {
            float v = o[i][j] * inv;
            bf16_t hh, ll; split2(v, hh, ll);
            hv[j] = hh; lv[j] = ll;
        }
        size_t idx = (size_t)(b * S_ + q0 + ty * 4 + i) * 1024 + h * 64 + tx * 4;
        *(bf16x4*)(Ohi + idx) = hv;
        *(bf16x4*)(Olo + idx) = lv;
    }
}

// ---------------- gate: affinities + top-2 membership -> priority [NR][T] ----------------
__global__ __launch_bounds__(256) void gate_kernel(const float* __restrict__ xn2, const float* __restrict__ Wg,
                                                   const float* __restrict__ bias, float* __restrict__ pri) {
    __shared__ float red[256][8];
    int t = blockIdx.x, tid = threadIdx.x;
    float acc[7] = {0.f, 0.f, 0.f, 0.f, 0.f, 0.f, 0.f};
    for (int d = tid; d < D_; d += 256) {
        float xv = xn2[(size_t)t * D_ + d];
        const float* wr = Wg + d * 7;
#pragma unroll
        for (int e = 0; e < 7; e++) acc[e] = fmaf(xv, wr[e], acc[e]);
    }
#pragma unroll
    for (int e = 0; e < 7; e++) red[tid][e] = acc[e];
    __syncthreads();
    for (int s2 = 128; s2 > 0; s2 >>= 1) {
        if (tid < s2) {
#pragma unroll
            for (int e = 0; e < 7; e++) red[tid][e] += red[tid + s2][e];
        }
        __syncthreads();
    }
    if (tid == 0) {
        float a[7];
#pragma unroll
        for (int e = 0; e < 7; e++) a[e] = 1.f / (1.f + expf(-(red[0][e] + bias[e])));
        int e1 = 0;
#pragma unroll
        for (int e = 1; e < 7; e++) if (a[e] > a[e1]) e1 = e;     // strict > : lowest-index tiebreak
        int e2 = -1;
#pragma unroll
        for (int e = 0; e < 7; e++) if (e != e1 && (e2 < 0 || a[e] > a[e2])) e2 = e;
#pragma unroll
        for (int e = 0; e < 7; e++) pri[(size_t)e * T_ + t] = (e == e1 || e == e2) ? a[e] : -1.f;
    }
}

// ---------------- exact top-585 via 32-step binary threshold search (order-free slots) ----------------
__global__ __launch_bounds__(1024) void select_kernel(const float* __restrict__ pri, int* __restrict__ sel_idx,
                                                      float* __restrict__ sel_w, int* __restrict__ inv_cnt,
                                                      int* __restrict__ inv_pair) {
    __shared__ u32 keys[T_];        // 16 KB: float bits (monotone for positive floats); 0 = invalid
    __shared__ int redc[16];
    __shared__ int bcast;
    __shared__ int ctr;
    const int e = blockIdx.x, tid = threadIdx.x;
    const int lane = tid & 63, wid = tid >> 6;
#pragma unroll
    for (int i = 0; i < 4; i++) {
        int idx = tid + i * 1024;
        float p = pri[(size_t)e * T_ + idx];
        keys[idx] = (p > 0.f) ? __float_as_uint(p) : 0u;
    }
    if (tid == 0) ctr = 0;
    __syncthreads();

    u32 myk[4];
#pragma unroll
    for (int i = 0; i < 4; i++) myk[i] = keys[tid + i * 1024];

    // binary search: p = max t with count(keys >= t) >= CAP  (= CAP-th largest key, or 0 if < CAP valid)
    u32 p = 0;
    for (int b = 31; b >= 0; b--) {
        u32 t = p | (1u << b);
        int cnt = 0;
#pragma unroll
        for (int i = 0; i < 4; i++) cnt += (myk[i] >= t) ? 1 : 0;
#pragma unroll
        for (int off = 32; off > 0; off >>= 1) cnt += __shfl_down(cnt, off);
        if (lane == 0) redc[wid] = cnt;
        __syncthreads();
        if (tid == 0) {
            int tot = 0;
#pragma unroll
            for (int k2 = 0; k2 < 16; k2++) tot += redc[k2];
            bcast = tot;
        }
        __syncthreads();
        if (bcast >= CAP_) p = t;
        __syncthreads();
    }
    // count strictly greater
    {
        int cnt = 0;
#pragma unroll
        for (int i = 0; i < 4; i++) cnt += (myk[i] > p) ? 1 : 0;
#pragma unroll
        for (int off = 32; off > 0; off >>= 1) cnt += __shfl_down(cnt, off);
        if (lane == 0) redc[wid] = cnt;
        __syncthreads();
        if (tid == 0) {
            int tot = 0;
#pragma unroll
            for (int k2 = 0; k2 < 16; k2++) tot += redc[k2];
            bcast = tot;
        }
        __syncthreads();
    }
    int cntGT = bcast;
    int quota = CAP_ - cntGT;   // slots left for keys == p (>=1 when p>0)

    // assignment: kept = (k > p) or (k == p, p>0, index-rank < quota)
#pragma unroll
    for (int i = 0; i < 4; i++) {
        int idx = tid + i * 1024;
        u32 k = myk[i];
        bool kept = false;
        if (k > p) kept = true;
        else if (k == p && p != 0u) {
            int rank = 0;
            for (int j = 0; j < idx; j++) rank += (keys[j] == p) ? 1 : 0;
            kept = (rank < quota);
        }
        if (kept) {
            int s = atomicAdd(&ctr, 1);
            sel_idx[e * CAP_ + s] = idx;
            sel_w[e * CAP_ + s] = __uint_as_float(k);
            int pos = atomicAdd(&inv_cnt[idx], 1);
            inv_pair[idx * 2 + pos] = e * CAP_ + s;
        }
    }
    __syncthreads();
    for (int s = ctr + tid; s < CAP_; s += 1024) {  // unfilled slots -> token 0, weight 0
        sel_idx[e * CAP_ + s] = 0;
        sel_w[e * CAP_ + s] = 0.f;
    }
}

// ---------------- transpose + convert: out[z][n][k] = (bf16) in[z][k][nbase+n] ----------------
__global__ __launch_bounds__(256) void packT_kernel(const float* __restrict__ in, bf16_t* __restrict__ out,
                                                    int K, int N, int nbase,
                                                    long long inStride, long long outStride) {
    __shared__ float tile[32][33];
    const int z = blockIdx.z;
    const int k0 = blockIdx.x * 32, n0 = blockIdx.y * 32;
    const int rr = threadIdx.x >> 5, cc = threadIdx.x & 31;
    const float* inz = in + (size_t)z * inStride;
#pragma unroll
    for (int it = 0; it < 4; it++) {
        int k = k0 + rr + it * 8;
        tile[rr + it * 8][cc] = inz[(size_t)k * N + nbase + n0 + cc];
    }
    __syncthreads();
    bf16_t* outz = out + (size_t)z * outStride;
#pragma unroll
    for (int it = 0; it < 4; it++) {
        int nl = n0 + rr + it * 8;
        outz[(size_t)nl * K + k0 + cc] = (bf16_t)tile[cc][rr + it * 8];
    }
}

// ---------------- bf16 MFMA GEMM (single precision pass, experts): C = gather(A) @ Bt^T (*scale) ----------------
template <bool GATHER, bool SCALE, bool OUTBF16>
__global__ __launch_bounds__(256) void mfma_gemm_kernel(const bf16_t* __restrict__ A, const bf16_t* __restrict__ Bt,
                                                        void* __restrict__ Cv,
                                                        const int* __restrict__ gidx, const float* __restrict__ scale,
                                                        int M, int K, int lda, int ldc,
                                                        long long strideA, long long strideBt, long long strideC,
                                                        int gstride) {
    __shared__ __align__(16) bf16_t As[128 * 32];
    __shared__ __align__(16) bf16_t Bs[128 * 32];
    const int tid = threadIdx.x;
    const int lane = tid & 63, w = tid >> 6;
    const int wm = (w & 1) * 64, wn = (w >> 1) * 64;
    const int z = blockIdx.z;
    const int m0 = blockIdx.y * 128, n0 = blockIdx.x * 128;
    const bf16_t* Az = A + (GATHER ? 0 : (size_t)z * strideA);
    const bf16_t* Bz = Bt + (size_t)z * strideBt;

    int arow[2];
#pragma unroll
    for (int i = 0; i < 2; i++) {
        int chunk = tid + i * 256;
        int r = m0 + (chunk >> 2);
        if (r > M - 1) r = M - 1;
        arow[i] = GATHER ? gidx[z * gstride + r] : r;
    }

    f32x4 acc[4][4];
#pragma unroll
    for (int mi = 0; mi < 4; mi++)
#pragma unroll
        for (int ni = 0; ni < 4; ni++) { f32x4 zz = {0.f, 0.f, 0.f, 0.f}; acc[mi][ni] = zz; }

    const int mrow = lane & 15, q = lane >> 4;
    for (int k0 = 0; k0 < K; k0 += 32) {
#pragma unroll
        for (int i = 0; i < 2; i++) {
            int chunk = tid + i * 256;
            int row = chunk >> 2, koff = (chunk & 3) * 8;
            *(uint4*)(As + row * 32 + koff) = *(const uint4*)(Az + (size_t)arow[i] * lda + k0 + koff);
            *(uint4*)(Bs + row * 32 + koff) = *(const uint4*)(Bz + (size_t)(n0 + row) * K + k0 + koff);
        }
        __syncthreads();
        bf16x8 af[4], bfr[4];
#pragma unroll
        for (int mi = 0; mi < 4; mi++)
            af[mi] = *(const bf16x8*)(As + (wm + mi * 16 + mrow) * 32 + q * 8);
#pragma unroll
        for (int ni = 0; ni < 4; ni++)
            bfr[ni] = *(const bf16x8*)(Bs + (wn + ni * 16 + mrow) * 32 + q * 8);
#pragma unroll
        for (int mi = 0; mi < 4; mi++)
#pragma unroll
            for (int ni = 0; ni < 4; ni++)
                acc[mi][ni] = __builtin_amdgcn_mfma_f32_16x16x32_bf16(af[mi], bfr[ni], acc[mi][ni], 0, 0, 0);
        __syncthreads();
    }
#pragma unroll
    for (int mi = 0; mi < 4; mi++) {
        int rbase = m0 + wm + mi * 16 + q * 4;
#pragma unroll
        for (int v = 0; v < 4; v++) {
            int r = rbase + v;
            if (r < M) {
                float sc = SCALE ? scale[z * gstride + r] : 1.f;
#pragma unroll
                for (int ni = 0; ni < 4; ni++) {
                    int c = n0 + wn + ni * 16 + mrow;
                    float val = acc[mi][ni][v];
                    if (SCALE) val *= sc;
                    size_t off = (size_t)z * strideC + (size_t)r * ldc + c;
                    if (OUTBF16) ((bf16_t*)Cv)[off] = (bf16_t)val;
                    else         ((float*)Cv)[off] = val;
                }
            }
        }
    }
}

// ---------------- SwiGLU elementwise ----------------
__global__ __launch_bounds__(256) void swiglu_kernel(const bf16_t* __restrict__ h, bf16_t* __restrict__ act,
                                                     int rows) {
    int i8 = blockIdx.x * 256 + threadIdx.x;
    int total = rows * 128;
    if (i8 >= total) return;
    int r = i8 >> 7, f = (i8 & 127) * 8;
    bf16x8 h1 = *(const bf16x8*)(h + (size_t)r * 2048 + f);
    bf16x8 h2 = *(const bf16x8*)(h + (size_t)r * 2048 + 1024 + f);
    bf16x8 o;
#pragma unroll
    for (int j = 0; j < 8; j++) {
        float a = (float)h1[j], g = (float)h2[j];
        o[j] = (bf16_t)(a * g / (1.f + __expf(-g)));
    }
    *(bf16x8*)(act + (size_t)r * 1024 + f) = o;
}

// ---------------- final combine: out = x1 + shared + sum routed ----------------
__global__ __launch_bounds__(256) void final_kernel(const float* __restrict__ x1, const float* __restrict__ sh,
                                                    const float* __restrict__ eout, const int* __restrict__ icnt,
                                                    const int* __restrict__ ipair, float* __restrict__ out) {
    int t = blockIdx.x, c = threadIdx.x * 4;
    float4 v = *(const float4*)(x1 + (size_t)t * D_ + c);
    float4 s2 = *(const float4*)(sh + (size_t)t * D_ + c);
    v.x += s2.x; v.y += s2.y; v.z += s2.z; v.w += s2.w;
    int n = icnt[t];
    for (int p = 0; p < n; p++) {
        int row = ipair[t * 2 + p];
        float4 ev = *(const float4*)(eout + (size_t)row * D_ + c);
        v.x += ev.x; v.y += ev.y; v.z += ev.z; v.w += ev.w;
    }
    *(float4*)(out + (size_t)t * D_ + c) = v;
}

// ---------------- launch ----------------
extern "C" void kernel_launch(void* const* d_in, const int* in_sizes, int n_in,
                              void* d_out, int out_size, void* d_ws, size_t ws_size,
                              hipStream_t stream) {
    (void)in_sizes; (void)n_in; (void)out_size; (void)ws_size;
    const float* x       = (const float*)d_in[0];
    const float* Wq_lat  = (const float*)d_in[2];
    const float* Wkv_lat = (const float*)d_in[3];
    const float* Wrot_q  = (const float*)d_in[4];
    const float* Wrot_k  = (const float*)d_in[5];
    const float* Wq_up   = (const float*)d_in[6];
    const float* Wk_up   = (const float*)d_in[7];
    const float* Wv_up   = (const float*)d_in[8];
    const float* Wout    = (const float*)d_in[9];
    const float* n1w     = (const float*)d_in[10];
    const float* n2w     = (const float*)d_in[11];
    const float* Ws1     = (const float*)d_in[12];
    const float* Ws2     = (const float*)d_in[13];
    const float* Wr1     = (const float*)d_in[14];
    const float* Wr2     = (const float*)d_in[15];
    const float* Wgate   = (const float*)d_in[16];
    const float* ebias   = (const float*)d_in[17];
    float* out = (float*)d_out;

    char* wsb = (char*)d_ws;
    // phase-1 pointers
    bf16_t* xnhi = (bf16_t*)(wsb + OFF_R0);
    bf16_t* xnlo = (bf16_t*)(wsb + OFF_R0 + 8 * MB_);
    bf16_t* zlhi = (bf16_t*)(wsb + OFF_R1);
    bf16_t* zllo = (bf16_t*)(wsb + OFF_R1 + 6 * MB_);
    float*  plat = (float*)(wsb + OFF_PLAT);
    float*  pqc  = (float*)(wsb + OFF_PQC);
    float*  pkv  = (float*)(wsb + OFF_PKV);
    bf16_t* plth = (bf16_t*)(wsb + OFF_PLTH);
    bf16_t* pltl = (bf16_t*)(wsb + OFF_PLTL);
    bf16_t* pqth = (bf16_t*)(wsb + OFF_PQTH);
    bf16_t* pqtl = (bf16_t*)(wsb + OFF_PQTL);
    bf16_t* pkth = (bf16_t*)(wsb + OFF_PKTH);
    bf16_t* pktl = (bf16_t*)(wsb + OFF_PKTL);
    bf16_t* woth = (bf16_t*)(wsb + OFF_WOTH);
    bf16_t* wotl = (bf16_t*)(wsb + OFF_WOTL);
    float*  qb   = (float*)(wsb + OFF_R2);
    float*  kvb  = (float*)(wsb + OFF_R3);
    bf16_t* atth = (bf16_t*)(wsb + OFF_R0);            // att splits reuse R0 (xn dead after zlat GEMM)
    bf16_t* attl = (bf16_t*)(wsb + OFF_R0 + 8 * MB_);
    float*  x1   = (float*)(wsb + OFF_X1);
    float*  cost = (float*)(wsb + OFF_COS);
    float*  sint = (float*)(wsb + OFF_SIN);
    // phase-2 pointers
    float*  xn2  = (float*)(wsb + OFF_R0);             // f32 for gate (att splits dead after Wout GEMM)
    bf16_t* Wr2T = (bf16_t*)(wsb + OFF_R0);            // after gate
    bf16_t* xnb  = (bf16_t*)(wsb + OFF_R1);
    bf16_t* Ws1T = (bf16_t*)(wsb + OFF_R1 + 8 * MB_);
    bf16_t* hbuf = (bf16_t*)(wsb + OFF_R2);
    bf16_t* actb = (bf16_t*)(wsb + OFF_R3);
    float*  eout = (float*)(wsb + OFF_R3 + 8 * MB_);
    bf16_t* Wr1H = (bf16_t*)(wsb + OFF_R4);
    float*  shout = (float*)(wsb + OFF_R4);
    bf16_t* Ws2T = (bf16_t*)(wsb + OFF_WS2T);
    float*  pri  = (float*)(wsb + OFF_PRI);
    int*    seli = (int*)(wsb + OFF_SELI);
    float*  selw = (float*)(wsb + OFF_SELW);
    int*    icnt = (int*)(wsb + OFF_ICNT);
    int*    ipr  = (int*)(wsb + OFF_IPR);

    // --- sublayer 1: attention path (bf16x3 MFMA GEMMs, fp32 flash attention) ---
    rmsnorm_kernel<0><<<T_, 256, 0, stream>>>(x, n1w, nullptr, xnhi, xnlo);
    pack_w_kernel<<<7168, 256, 0, stream>>>(Wq_lat, Wkv_lat, Wq_up, Wrot_q, Wk_up, Wrot_k, Wv_up,
                                            plat, pqc, pkv);
    rope_table_kernel<<<(S_ * 16) / 256, 256, 0, stream>>>(cost, sint);
    packTsplit_kernel<<<dim3(32, 24), 256, 0, stream>>>(plat, plth, pltl, 1024, 768);
    packTsplit_kernel<<<dim3(16, 32), 256, 0, stream>>>(pqc, pqth, pqtl, 512, 1024);
    packTsplit_kernel<<<dim3(8, 64), 256, 0, stream>>>(pkv, pkth, pktl, 256, 2048);
    packTsplit_kernel<<<dim3(32, 32), 256, 0, stream>>>(Wout, woth, wotl, 1024, 1024);
    // zlat = xn @ PLAT : 4096x768x1024, split output
    mfma3_gemm_kernel<false, 1><<<dim3(6, 32), 256, 0, stream>>>(
        xnhi, xnlo, plth, pltl, nullptr, zlhi, zllo, nullptr, 1024, 1024, 768);
    // q = zlat[:, :512] @ PQC : 4096x1024x512, f32 out
    mfma3_gemm_kernel<false, 0><<<dim3(8, 32), 256, 0, stream>>>(
        zlhi, zllo, pqth, pqtl, qb, nullptr, nullptr, nullptr, 512, 768, 1024);
    // k|v = zlat[:, 512:768] @ PKV : 4096x2048x256, f32 out
    mfma3_gemm_kernel<false, 0><<<dim3(16, 32), 256, 0, stream>>>(
        zlhi + 512, zllo + 512, pkth, pktl, kvb, nullptr, nullptr, nullptr, 256, 768, 2048);
    rope_apply_kernel<<<(T_ * H_) / 256, 256, 0, stream>>>(qb, kvb, cost, sint);
    attn_kernel<<<dim3(1024), 256, 0, stream>>>(qb, kvb, atth, attl);
    // x1 = att @ Wout + x : 4096x1024x1024
    mfma3_gemm_kernel<true, 0><<<dim3(8, 32), 256, 0, stream>>>(
        atth, attl, woth, wotl, x1, nullptr, nullptr, x, 1024, 1024, 1024);

    // --- sublayer 2: MoE ---
    rmsnorm_kernel<1><<<T_, 256, 0, stream>>>(x1, n2w, xn2, xnb, nullptr);
    hipMemsetAsync(icnt, 0, T_ * sizeof(int), stream);
    gate_kernel<<<T_, 256, 0, stream>>>(xn2, Wgate, ebias, pri);           // fp32 gate
    select_kernel<<<NR_, 1024, 0, stream>>>(pri, seli, selw, icnt, ipr);   // exact top-CAP

    // weight packs (R0 free after gate)
    packT_kernel<<<dim3(32, 32, 7), 256, 0, stream>>>(Wr2, Wr2T, 1024, 1024, 0,
                                                      (long long)1024 * 1024, (long long)1024 * 1024);
    packT_kernel<<<dim3(32, 64, 1), 256, 0, stream>>>(Ws1, Ws1T, 1024, 2048, 0, 0, 0);
    packT_kernel<<<dim3(32, 32, 1), 256, 0, stream>>>(Ws2, Ws2T, 1024, 1024, 0, 0, 0);

    // routed experts (Wr1 halves staged through R4)
    packT_kernel<<<dim3(32, 32, 7), 256, 0, stream>>>(Wr1, Wr1H, 1024, 2048, 0,
                                                      (long long)1024 * 2048, (long long)1024 * 1024);
    mfma_gemm_kernel<true, false, true><<<dim3(8, 5, 7), 256, 0, stream>>>(
        xnb, Wr1H, hbuf, seli, nullptr, CAP_, 1024, 1024, 2048,
        0, (long long)1024 * 1024, (long long)CAP_ * 2048, CAP_);
    packT_kernel<<<dim3(32, 32, 7), 256, 0, stream>>>(Wr1, Wr1H, 1024, 2048, 1024,
                                                      (long long)1024 * 2048, (long long)1024 * 1024);
    mfma_gemm_kernel<true, false, true><<<dim3(8, 5, 7), 256, 0, stream>>>(
        xnb, Wr1H, hbuf + 1024, seli, nullptr, CAP_, 1024, 1024, 2048,
        0, (long long)1024 * 1024, (long long)CAP_ * 2048, CAP_);
    swiglu_kernel<<<(NR_ * CAP_ * 128 + 255) / 256, 256, 0, stream>>>(hbuf, actb, NR_ * CAP_);
    mfma_gemm_kernel<false, true, false><<<dim3(8, 5, 7), 256, 0, stream>>>(
        actb, Wr2T, eout, nullptr, selw, CAP_, 1024, 1024, 1024,
        (long long)CAP_ * 1024, (long long)1024 * 1024, (long long)CAP_ * 1024, CAP_);

    // shared expert (R4 free -> shout)
    mfma_gemm_kernel<false, false, true><<<dim3(16, 32, 1), 256, 0, stream>>>(
        xnb, Ws1T, hbuf, nullptr, nullptr, T_, 1024, 1024, 2048, 0, 0, 0, 0);
    swiglu_kernel<<<(T_ * 128 + 255) / 256, 256, 0, stream>>>(hbuf, actb, T_);
    mfma_gemm_kernel<false, false, false><<<dim3(8, 32, 1), 256, 0, stream>>>(
        actb, Ws2T, shout, nullptr, nullptr, T_, 1024, 1024, 1024, 0, 0, 0, 0);

    // combine
    final_kernel<<<T_, 256, 0, stream>>>(x1, shout, eout, icnt, ipr, out);
}